// Round 1
// baseline (2103.463 us; speedup 1.0000x reference)
//
#include <hip/hip_runtime.h>
#include <cstdint>

#define B_    4
#define S_    2048
#define D_    1024
#define NIN   8192
#define NPROC 4096
#define DR    256
#define DR2   512
#define KIN   4096
#define KPROC 2048

typedef _Float16 v8h __attribute__((ext_vector_type(8)));
typedef _Float16 v4h __attribute__((ext_vector_type(4)));
typedef float    v4f __attribute__((ext_vector_type(4)));

__device__ __forceinline__ float geluf(float v) {
    return 0.5f * v * (1.0f + erff(v * 0.70710678f));
}

// async global->LDS, 16B per lane. LDS dest semantics: wave-uniform base + lane*16.
__device__ __forceinline__ void cp16(void* lds, const void* g) {
    __builtin_amdgcn_global_load_lds(
        (const __attribute__((address_space(1))) unsigned int*)g,
        (__attribute__((address_space(3))) unsigned int*)lds, 16, 0, 0);
}

// ---------------- converts ----------------
__global__ void k_conv_x16(const float* __restrict__ x, _Float16* __restrict__ x16, int n4) {
    int i = blockIdx.x * 256 + threadIdx.x;
    if (i < n4) {
        float4 v = ((const float4*)x)[i];
        v4h h = { (_Float16)v.x, (_Float16)v.y, (_Float16)v.z, (_Float16)v.w };
        ((v4h*)x16)[i] = h;
    }
}

__global__ void k_conv_split(const float* __restrict__ p, _Float16* __restrict__ ph,
                             _Float16* __restrict__ pl, int n) {
    int i = blockIdx.x * 256 + threadIdx.x;
    if (i < n) {
        float v = p[i];
        _Float16 h = (_Float16)v;
        ph[i] = h;
        pl[i] = (_Float16)(v - (float)h);
    }
}

// ---------------- gc = max over s ----------------
__global__ void k_max1(const float* __restrict__ x, float* __restrict__ pmax) {
    int d = blockIdx.x * 256 + threadIdx.x;   // grid.x = 4
    int chunk = blockIdx.y;                   // 16
    int b = blockIdx.z;                       // 4
    const float* base = x + ((size_t)b * S_ + chunk * 128) * D_ + d;
    float m = -3.4e38f;
    for (int s = 0; s < 128; s++) m = fmaxf(m, base[(size_t)s * D_]);
    pmax[((size_t)b * 16 + chunk) * D_ + d] = m;
}

__global__ void k_max2(const float* __restrict__ pmax, double* __restrict__ gc64) {
    int d = blockIdx.x * 256 + threadIdx.x;   // grid.x = 4
    int b = blockIdx.y;
    float m = -3.4e38f;
    for (int c = 0; c < 16; c++) m = fmaxf(m, pmax[((size_t)b * 16 + c) * D_ + d]);
    gc64[(size_t)b * D_ + d] = (double)m;
}

// ---------------- router (fp64): gelu -> LN -> query -> logits ----------------
__global__ __launch_bounds__(512) void k_router(
    const double* __restrict__ gc64, const float* __restrict__ W1, const float* __restrict__ b1,
    const float* __restrict__ lng, const float* __restrict__ lnb,
    const float* __restrict__ W2, const float* __restrict__ b2,
    const float* __restrict__ keys, double* __restrict__ logits)
{
    __shared__ double sh[DR2];
    __shared__ double red[DR2];
    __shared__ double qs[DR];
    int b = blockIdx.x, j = threadIdx.x;
    const double* g = gc64 + (size_t)b * D_;
    double acc = (double)b1[j];
    const float* w1r = W1 + (size_t)j * D_;
    for (int d = 0; d < D_; d++) acc += g[d] * (double)w1r[d];
    double ge = 0.5 * acc * (1.0 + erf(acc * 0.7071067811865475244));
    sh[j] = ge; red[j] = ge;
    __syncthreads();
    for (int s = 256; s > 0; s >>= 1) { if (j < s) red[j] += red[j + s]; __syncthreads(); }
    double mu = red[0] / 512.0;
    __syncthreads();
    double dv = sh[j] - mu;
    red[j] = dv * dv;
    __syncthreads();
    for (int s = 256; s > 0; s >>= 1) { if (j < s) red[j] += red[j + s]; __syncthreads(); }
    double var = red[0] / 512.0;
    double rs = 1.0 / sqrt(var + 1e-5);
    __syncthreads();
    sh[j] = dv * rs * (double)lng[j] + (double)lnb[j];
    __syncthreads();
    if (j < DR) {
        double q = (double)b2[j];
        const float* w2r = W2 + (size_t)j * DR2;
        for (int t = 0; t < DR2; t++) q += sh[t] * (double)w2r[t];
        qs[j] = q;
    }
    __syncthreads();
    for (int n = j; n < NIN; n += 512) {
        const float* kr = keys + (size_t)n * DR;
        double a3 = 0.0;
        for (int d = 0; d < DR; d++) a3 += qs[d] * (double)kr[d];
        logits[(size_t)b * NIN + n] = a3 * 0.0625;   // / sqrt(256)
    }
}

// ---------------- top-k: in-LDS bitonic sort of (value,~idx) keys, descending ----------------
template<int N, int K>
__global__ __launch_bounds__(1024) void k_topk(const double* __restrict__ vals, int* __restrict__ outIdx) {
    __shared__ unsigned long long keys[N];
    int b = blockIdx.x, tid = threadIdx.x;
    for (int i = tid; i < N; i += 1024) {
        float v = (float)vals[(size_t)b * N + i];
        unsigned int u = __float_as_uint(v);
        u = (u & 0x80000000u) ? ~u : (u | 0x80000000u);
        keys[i] = ((unsigned long long)u << 32) | (unsigned int)(~i);
    }
    __syncthreads();
    for (int k = 2; k <= N; k <<= 1)
        for (int j = k >> 1; j > 0; j >>= 1) {
            for (int i = tid; i < N; i += 1024) {
                int l = i ^ j;
                if (l > i) {
                    unsigned long long a = keys[i], c = keys[l];
                    bool up = ((i & k) == 0);
                    if ((a < c) == up) { keys[i] = c; keys[l] = a; }
                }
            }
            __syncthreads();
        }
    for (int i = tid; i < K; i += 1024)
        outIdx[(size_t)b * K + i] = (int)(~(unsigned int)keys[i]);
}

// ---------------- gathers ----------------
__global__ void k_gatherW(const float* __restrict__ pw, const int* __restrict__ iidx,
                          _Float16* __restrict__ Wh, _Float16* __restrict__ Wl, int b) {
    int p = blockIdx.x;
    const float* row = pw + (size_t)p * NIN;
    const int* ix = iidx + (size_t)b * KIN;
    for (int j = threadIdx.x; j < KIN; j += 256) {
        float w = row[ix[j]];
        _Float16 h = (_Float16)w;
        Wh[(size_t)p * KIN + j] = h;
        Wl[(size_t)p * KIN + j] = (_Float16)(w - (float)h);
    }
}

__global__ void k_gatherSP(const _Float16* __restrict__ acts16, const int* __restrict__ pidx,
                           _Float16* __restrict__ sp) {
    int s = blockIdx.x, b = blockIdx.y;
    const _Float16* arow = acts16 + ((size_t)b * S_ + s) * NPROC;
    _Float16* orow = sp + ((size_t)b * S_ + s) * KPROC;
    const int* pi = pidx + (size_t)b * KPROC;
    for (int k = threadIdx.x; k < KPROC; k += 256) orow[k] = arow[pi[k]];
}

__global__ void k_gatherWoT(const _Float16* __restrict__ pout16, const int* __restrict__ pidx,
                            _Float16* __restrict__ woT) {
    __shared__ _Float16 t[64][65];
    int k0 = blockIdx.x * 64, d0 = blockIdx.y * 64, b = blockIdx.z;
    const int* pi = pidx + (size_t)b * KPROC;
    for (int i = threadIdx.x; i < 4096; i += 256) {
        int kk = i >> 6, dd = i & 63;
        t[kk][dd] = pout16[(size_t)pi[k0 + kk] * D_ + d0 + dd];
    }
    __syncthreads();
    for (int i = threadIdx.x; i < 4096; i += 256) {
        int dd = i >> 6, kk = i & 63;
        woT[((size_t)b * D_ + d0 + dd) * KPROC + k0 + kk] = t[kk][dd];
    }
}

// ---------------- stage D: sel_acts = gelu(x16 * (ph+pl)^T) on gathered pattern rows ----------------
__global__ __launch_bounds__(256) void k_gemmD(
    const _Float16* __restrict__ x16, const _Float16* __restrict__ ph, const _Float16* __restrict__ pl,
    const int* __restrict__ iidx, _Float16* __restrict__ a16)
{
    const int b = blockIdx.z;
    const int m0 = blockIdx.x * 128, n0 = blockIdx.y * 128;
    __shared__ _Float16 tA[4096], tBh[4096], tBl[4096];
    const int tid = threadIdx.x, lane = tid & 63;
    const int wave = tid >> 6, wrow = wave >> 1, wcol = wave & 1;
    const int srow = tid >> 2, spart = tid & 3;

    const _Float16* as0 = x16 + ((size_t)b * S_ + m0 + srow) * D_ + spart * 8;
    const _Float16* as1 = as0 + (size_t)64 * D_;
    int r0 = iidx[(size_t)b * KIN + n0 + srow];
    int r1 = iidx[(size_t)b * KIN + n0 + srow + 64];
    const _Float16* bh0 = ph + (size_t)r0 * D_ + spart * 8;
    const _Float16* bh1 = ph + (size_t)r1 * D_ + spart * 8;
    const _Float16* bl0 = pl + (size_t)r0 * D_ + spart * 8;
    const _Float16* bl1 = pl + (size_t)r1 * D_ + spart * 8;

    v4f acc[4][4];
    v4f z = {0.f, 0.f, 0.f, 0.f};
#pragma unroll
    for (int i = 0; i < 4; i++)
#pragma unroll
        for (int j = 0; j < 4; j++) acc[i][j] = z;

    const int aoff = (wrow * 64 + (lane & 15)) * 32 + (lane >> 4) * 8;
    const int boff = (wcol * 64 + (lane & 15)) * 32 + (lane >> 4) * 8;

    for (int kt = 0; kt < D_; kt += 32) {
        __syncthreads();
        cp16(&tA[tid * 8], as0 + kt);
        cp16(&tA[2048 + tid * 8], as1 + kt);
        cp16(&tBh[tid * 8], bh0 + kt);
        cp16(&tBh[2048 + tid * 8], bh1 + kt);
        cp16(&tBl[tid * 8], bl0 + kt);
        cp16(&tBl[2048 + tid * 8], bl1 + kt);
        asm volatile("s_waitcnt vmcnt(0)" ::: "memory");
        __syncthreads();
        v8h af[4], fh[4], fl[4];
#pragma unroll
        for (int i = 0; i < 4; i++) af[i] = *(const v8h*)&tA[aoff + i * 512];
#pragma unroll
        for (int j = 0; j < 4; j++) {
            fh[j] = *(const v8h*)&tBh[boff + j * 512];
            fl[j] = *(const v8h*)&tBl[boff + j * 512];
        }
#pragma unroll
        for (int i = 0; i < 4; i++)
#pragma unroll
            for (int j = 0; j < 4; j++) {
                acc[i][j] = __builtin_amdgcn_mfma_f32_16x16x32_f16(af[i], fh[j], acc[i][j], 0, 0, 0);
                acc[i][j] = __builtin_amdgcn_mfma_f32_16x16x32_f16(af[i], fl[j], acc[i][j], 0, 0, 0);
            }
    }
    const int rbase = m0 + wrow * 64 + ((lane >> 4) << 2);
    const int cbase = n0 + wcol * 64 + (lane & 15);
#pragma unroll
    for (int i = 0; i < 4; i++)
#pragma unroll
        for (int j = 0; j < 4; j++)
#pragma unroll
            for (int r = 0; r < 4; r++) {
                float gv = geluf(acc[i][j][r]);
                a16[((size_t)b * S_ + rbase + i * 16 + r) * (size_t)KIN + cbase + j * 16] = (_Float16)gv;
            }
}

// ---------------- stage E: proc_acts = gelu(a16 * (Wh+Wl)^T), scores += column sums ----------------
__global__ __launch_bounds__(256) void k_gemmE(
    const _Float16* __restrict__ a16, const _Float16* __restrict__ Wh, const _Float16* __restrict__ Wl,
    _Float16* __restrict__ acts16, double* __restrict__ scores, int b)
{
    const int m0 = blockIdx.x * 128, n0 = blockIdx.y * 128;
    __shared__ _Float16 tA[4096], tBh[4096], tBl[4096];
    const int tid = threadIdx.x, lane = tid & 63;
    const int wave = tid >> 6, wrow = wave >> 1, wcol = wave & 1;
    const int srow = tid >> 2, spart = tid & 3;

    const _Float16* as0 = a16 + ((size_t)b * S_ + m0 + srow) * (size_t)KIN + spart * 8;
    const _Float16* as1 = as0 + (size_t)64 * KIN;
    const _Float16* bh0 = Wh + (size_t)(n0 + srow) * KIN + spart * 8;
    const _Float16* bh1 = bh0 + (size_t)64 * KIN;
    const _Float16* bl0 = Wl + (size_t)(n0 + srow) * KIN + spart * 8;
    const _Float16* bl1 = bl0 + (size_t)64 * KIN;

    v4f acc[4][4];
    v4f z = {0.f, 0.f, 0.f, 0.f};
#pragma unroll
    for (int i = 0; i < 4; i++)
#pragma unroll
        for (int j = 0; j < 4; j++) acc[i][j] = z;

    const int aoff = (wrow * 64 + (lane & 15)) * 32 + (lane >> 4) * 8;
    const int boff = (wcol * 64 + (lane & 15)) * 32 + (lane >> 4) * 8;

    for (int kt = 0; kt < KIN; kt += 32) {
        __syncthreads();
        cp16(&tA[tid * 8], as0 + kt);
        cp16(&tA[2048 + tid * 8], as1 + kt);
        cp16(&tBh[tid * 8], bh0 + kt);
        cp16(&tBh[2048 + tid * 8], bh1 + kt);
        cp16(&tBl[tid * 8], bl0 + kt);
        cp16(&tBl[2048 + tid * 8], bl1 + kt);
        asm volatile("s_waitcnt vmcnt(0)" ::: "memory");
        __syncthreads();
        v8h af[4], fh[4], fl[4];
#pragma unroll
        for (int i = 0; i < 4; i++) af[i] = *(const v8h*)&tA[aoff + i * 512];
#pragma unroll
        for (int j = 0; j < 4; j++) {
            fh[j] = *(const v8h*)&tBh[boff + j * 512];
            fl[j] = *(const v8h*)&tBl[boff + j * 512];
        }
#pragma unroll
        for (int i = 0; i < 4; i++)
#pragma unroll
            for (int j = 0; j < 4; j++) {
                acc[i][j] = __builtin_amdgcn_mfma_f32_16x16x32_f16(af[i], fh[j], acc[i][j], 0, 0, 0);
                acc[i][j] = __builtin_amdgcn_mfma_f32_16x16x32_f16(af[i], fl[j], acc[i][j], 0, 0, 0);
            }
    }
    const int rbase = m0 + wrow * 64 + ((lane >> 4) << 2);
    const int cbase = n0 + wcol * 64 + (lane & 15);
    float psum[4] = {0.f, 0.f, 0.f, 0.f};
#pragma unroll
    for (int i = 0; i < 4; i++)
#pragma unroll
        for (int j = 0; j < 4; j++)
#pragma unroll
            for (int r = 0; r < 4; r++) {
                float gv = geluf(acc[i][j][r]);
                acts16[((size_t)b * S_ + rbase + i * 16 + r) * (size_t)NPROC + cbase + j * 16] = (_Float16)gv;
                psum[j] += gv;
            }
#pragma unroll
    for (int j = 0; j < 4; j++) {
        float s = psum[j];
        s += __shfl_xor(s, 16, 64);
        s += __shfl_xor(s, 32, 64);
        if ((lane >> 4) == 0)
            atomicAdd(&scores[(size_t)b * NPROC + cbase + j * 16], (double)s);
    }
}

// ---------------- stage F: out = sp * woT^T (plain f16) ----------------
__global__ __launch_bounds__(256) void k_gemmF(
    const _Float16* __restrict__ sp, const _Float16* __restrict__ woT, float* __restrict__ out)
{
    const int b = blockIdx.z;
    const int m0 = blockIdx.x * 128, n0 = blockIdx.y * 128;
    __shared__ _Float16 tA[4096], tB[4096];
    const int tid = threadIdx.x, lane = tid & 63;
    const int wave = tid >> 6, wrow = wave >> 1, wcol = wave & 1;
    const int srow = tid >> 2, spart = tid & 3;

    const _Float16* as0 = sp + ((size_t)b * S_ + m0 + srow) * (size_t)KPROC + spart * 8;
    const _Float16* as1 = as0 + (size_t)64 * KPROC;
    const _Float16* bs0 = woT + ((size_t)b * D_ + n0 + srow) * (size_t)KPROC + spart * 8;
    const _Float16* bs1 = bs0 + (size_t)64 * KPROC;

    v4f acc[4][4];
    v4f z = {0.f, 0.f, 0.f, 0.f};
#pragma unroll
    for (int i = 0; i < 4; i++)
#pragma unroll
        for (int j = 0; j < 4; j++) acc[i][j] = z;

    const int aoff = (wrow * 64 + (lane & 15)) * 32 + (lane >> 4) * 8;
    const int boff = (wcol * 64 + (lane & 15)) * 32 + (lane >> 4) * 8;

    for (int kt = 0; kt < KPROC; kt += 32) {
        __syncthreads();
        cp16(&tA[tid * 8], as0 + kt);
        cp16(&tA[2048 + tid * 8], as1 + kt);
        cp16(&tB[tid * 8], bs0 + kt);
        cp16(&tB[2048 + tid * 8], bs1 + kt);
        asm volatile("s_waitcnt vmcnt(0)" ::: "memory");
        __syncthreads();
        v8h af[4], bf[4];
#pragma unroll
        for (int i = 0; i < 4; i++) af[i] = *(const v8h*)&tA[aoff + i * 512];
#pragma unroll
        for (int j = 0; j < 4; j++) bf[j] = *(const v8h*)&tB[boff + j * 512];
#pragma unroll
        for (int i = 0; i < 4; i++)
#pragma unroll
            for (int j = 0; j < 4; j++)
                acc[i][j] = __builtin_amdgcn_mfma_f32_16x16x32_f16(af[i], bf[j], acc[i][j], 0, 0, 0);
    }
    const int rbase = m0 + wrow * 64 + ((lane >> 4) << 2);
    const int cbase = n0 + wcol * 64 + (lane & 15);
#pragma unroll
    for (int i = 0; i < 4; i++)
#pragma unroll
        for (int j = 0; j < 4; j++)
#pragma unroll
            for (int r = 0; r < 4; r++)
                out[((size_t)b * S_ + rbase + i * 16 + r) * (size_t)D_ + cbase + j * 16] = acc[i][j][r];
}

// ---------------- host ----------------
extern "C" void kernel_launch(void* const* d_in, const int* in_sizes, int n_in,
                              void* d_out, int out_size, void* d_ws, size_t ws_size,
                              hipStream_t stream) {
    const float* x    = (const float*)d_in[0];
    const float* W1   = (const float*)d_in[1];
    const float* b1   = (const float*)d_in[2];
    const float* lng  = (const float*)d_in[3];
    const float* lnb  = (const float*)d_in[4];
    const float* W2   = (const float*)d_in[5];
    const float* b2   = (const float*)d_in[6];
    const float* keys = (const float*)d_in[7];
    const float* patt = (const float*)d_in[8];
    const float* pw   = (const float*)d_in[9];
    const float* pout = (const float*)d_in[10];
    (void)in_sizes; (void)n_in; (void)out_size;

    char* w = (char*)d_ws;
    size_t off = 0;
    auto alloc = [&](size_t bytes) -> void* {
        void* p = w + off;
        off += (bytes + 255) & ~(size_t)255;
        return p;
    };
    double* gc64   = (double*)alloc((size_t)B_ * D_ * 8);
    float*  pmax   = (float*) alloc((size_t)B_ * 16 * D_ * 4);
    double* logits = (double*)alloc((size_t)B_ * NIN * 8);
    double* scores = (double*)alloc((size_t)B_ * NPROC * 8);
    int*    iidx   = (int*)   alloc((size_t)B_ * KIN * 4);
    int*    pidx   = (int*)   alloc((size_t)B_ * KPROC * 4);
    _Float16* a16    = (_Float16*)alloc((size_t)B_ * S_ * KIN * 2);    // 67 MB
    _Float16* acts16 = (_Float16*)alloc((size_t)B_ * S_ * NPROC * 2);  // 67 MB
    _Float16* pout16 = (_Float16*)alloc((size_t)NPROC * D_ * 2);       // 8.4 MB
    // union region (67.1 MB): phase1 {x16, ph, pl}; phase2 {Wh, Wl}; phase3 {sp, woT}
    char* u1 = (char*)alloc((size_t)67108864);
    _Float16* x16 = (_Float16*)u1;
    _Float16* ph  = (_Float16*)(u1 + 16777216);
    _Float16* pl  = (_Float16*)(u1 + 33554432);
    _Float16* Wh  = (_Float16*)u1;
    _Float16* Wl  = (_Float16*)(u1 + 33554432);
    _Float16* sp  = (_Float16*)u1;
    _Float16* woT = (_Float16*)(u1 + 33554432);
    (void)ws_size; // total ~210 MB

    hipMemsetAsync(scores, 0, (size_t)B_ * NPROC * 8, stream);

    k_conv_x16 <<<dim3((B_ * S_ * D_ / 4 + 255) / 256), 256, 0, stream>>>(x, x16, B_ * S_ * D_ / 4);
    k_conv_split<<<dim3((NIN * D_ + 255) / 256), 256, 0, stream>>>(patt, ph, pl, NIN * D_);
    k_conv_x16 <<<dim3((NPROC * D_ / 4 + 255) / 256), 256, 0, stream>>>(pout, pout16, NPROC * D_ / 4);

    k_max1<<<dim3(4, 16, 4), 256, 0, stream>>>(x, pmax);
    k_max2<<<dim3(4, 4), 256, 0, stream>>>(pmax, gc64);
    k_router<<<dim3(4), 512, 0, stream>>>(gc64, W1, b1, lng, lnb, W2, b2, keys, logits);
    k_topk<NIN, KIN><<<dim3(4), 1024, 0, stream>>>(logits, iidx);

    k_gemmD<<<dim3(16, 32, 4), 256, 0, stream>>>(x16, ph, pl, iidx, a16);

    for (int b = 0; b < 4; b++) {
        k_gatherW<<<dim3(NPROC), 256, 0, stream>>>(pw, iidx, Wh, Wl, b);
        k_gemmE<<<dim3(16, 32), 256, 0, stream>>>(a16, Wh, Wl, acts16, scores, b);
    }

    k_topk<NPROC, KPROC><<<dim3(4), 1024, 0, stream>>>(scores, pidx);
    k_gatherSP<<<dim3(S_, 4), 256, 0, stream>>>(acts16, pidx, sp);
    k_gatherWoT<<<dim3(KPROC / 64, D_ / 64, 4), 256, 0, stream>>>(pout16, pidx, woT);
    k_gemmF<<<dim3(16, 8, 4), 256, 0, stream>>>(sp, woT, (float*)d_out);
}

// Round 2
// 1800.734 us; speedup vs baseline: 1.1681x; 1.1681x over previous
//
#include <hip/hip_runtime.h>
#include <cstdint>

#define B_    4
#define S_    2048
#define D_    1024
#define NIN   8192
#define NPROC 4096
#define DR    256
#define DR2   512
#define KIN   4096
#define KPROC 2048

typedef _Float16 v8h __attribute__((ext_vector_type(8)));
typedef _Float16 v4h __attribute__((ext_vector_type(4)));
typedef float    v4f __attribute__((ext_vector_type(4)));

__device__ __forceinline__ float geluf(float v) {
    return 0.5f * v * (1.0f + erff(v * 0.70710678f));
}

// async global->LDS, 16B per lane. LDS dest semantics: wave-uniform base + lane*16.
__device__ __forceinline__ void cp16(void* lds, const void* g) {
    __builtin_amdgcn_global_load_lds(
        (const __attribute__((address_space(1))) unsigned int*)g,
        (__attribute__((address_space(3))) unsigned int*)lds, 16, 0, 0);
}

// ---------------- converts ----------------
__global__ void k_conv_x16(const float* __restrict__ x, _Float16* __restrict__ x16, int n4) {
    int i = blockIdx.x * 256 + threadIdx.x;
    if (i < n4) {
        float4 v = ((const float4*)x)[i];
        v4h h = { (_Float16)v.x, (_Float16)v.y, (_Float16)v.z, (_Float16)v.w };
        ((v4h*)x16)[i] = h;
    }
}

__global__ void k_conv_split(const float* __restrict__ p, _Float16* __restrict__ ph,
                             _Float16* __restrict__ pl, int n) {
    int i = blockIdx.x * 256 + threadIdx.x;
    if (i < n) {
        float v = p[i];
        _Float16 h = (_Float16)v;
        ph[i] = h;
        pl[i] = (_Float16)(v - (float)h);
    }
}

// ---------------- gc = max over s ----------------
__global__ void k_max1(const float* __restrict__ x, float* __restrict__ pmax) {
    int d = blockIdx.x * 256 + threadIdx.x;   // grid.x = 4
    int chunk = blockIdx.y;                   // 16
    int b = blockIdx.z;                       // 4
    const float* base = x + ((size_t)b * S_ + chunk * 128) * D_ + d;
    float m = -3.4e38f;
    for (int s = 0; s < 128; s++) m = fmaxf(m, base[(size_t)s * D_]);
    pmax[((size_t)b * 16 + chunk) * D_ + d] = m;
}

__global__ void k_max2(const float* __restrict__ pmax, double* __restrict__ gc64) {
    int d = blockIdx.x * 256 + threadIdx.x;   // grid.x = 4
    int b = blockIdx.y;
    float m = -3.4e38f;
    for (int c = 0; c < 16; c++) m = fmaxf(m, pmax[((size_t)b * 16 + c) * D_ + d]);
    gc64[(size_t)b * D_ + d] = (double)m;
}

// ---------------- router stage 1: hpre[b][j] = gelu(gc . W1_j + b1_j), fp64 ----------------
// one wave per (b,j). grid (128, 4), block 256.
__global__ __launch_bounds__(256) void k_router1(
    const double* __restrict__ gc64, const float* __restrict__ W1, const float* __restrict__ b1,
    double* __restrict__ hpre)
{
    int wave = threadIdx.x >> 6, lane = threadIdx.x & 63;
    int j = blockIdx.x * 4 + wave;
    int b = blockIdx.y;
    const double* g = gc64 + (size_t)b * D_;
    const float* w = W1 + (size_t)j * D_;
    double acc = 0.0;
    for (int d = lane; d < D_; d += 64) acc += g[d] * (double)w[d];
#pragma unroll
    for (int o = 32; o > 0; o >>= 1) acc += __shfl_xor(acc, o, 64);
    if (lane == 0) {
        double z = acc + (double)b1[j];
        hpre[(size_t)b * DR2 + j] = 0.5 * z * (1.0 + erf(z * 0.7071067811865475244));
    }
}

// ---------------- router stage 2: LN + query, fp64. one block per batch ----------------
__global__ __launch_bounds__(512) void k_router2(
    const double* __restrict__ hpre, const float* __restrict__ lng, const float* __restrict__ lnb,
    const float* __restrict__ W2, const float* __restrict__ b2, double* __restrict__ qs)
{
    __shared__ double sh[DR2];
    __shared__ double red[DR2];
    int b = blockIdx.x, j = threadIdx.x;
    double ge = hpre[(size_t)b * DR2 + j];
    sh[j] = ge; red[j] = ge;
    __syncthreads();
    for (int s = 256; s > 0; s >>= 1) { if (j < s) red[j] += red[j + s]; __syncthreads(); }
    double mu = red[0] / 512.0;
    __syncthreads();
    double dv = ge - mu;
    red[j] = dv * dv;
    __syncthreads();
    for (int s = 256; s > 0; s >>= 1) { if (j < s) red[j] += red[j + s]; __syncthreads(); }
    double rs = 1.0 / sqrt(red[0] / 512.0 + 1e-5);
    __syncthreads();
    sh[j] = dv * rs * (double)lng[j] + (double)lnb[j];
    __syncthreads();
    if (j < DR) {
        double q = (double)b2[j];
        const float* w2r = W2 + (size_t)j * DR2;
        for (int t = 0; t < DR2; t++) q += sh[t] * (double)w2r[t];
        qs[(size_t)b * DR + j] = q;
    }
}

// ---------------- router stage 3: logits, fp64. one wave per (b,n). grid (2048,4) ----------------
__global__ __launch_bounds__(256) void k_router3(
    const double* __restrict__ qs, const float* __restrict__ keys, double* __restrict__ logits)
{
    int wave = threadIdx.x >> 6, lane = threadIdx.x & 63;
    int n = blockIdx.x * 4 + wave;
    int b = blockIdx.y;
    const double* q = qs + (size_t)b * DR;
    const float* kr = keys + (size_t)n * DR;
    double acc = 0.0;
#pragma unroll
    for (int t = 0; t < 4; t++) {
        int d = lane + t * 64;
        acc += q[d] * (double)kr[d];
    }
#pragma unroll
    for (int o = 32; o > 0; o >>= 1) acc += __shfl_xor(acc, o, 64);
    if (lane == 0) logits[(size_t)b * NIN + n] = acc * 0.0625;  // / sqrt(256)
}

// ---------------- top-k: in-LDS bitonic sort of (value,~idx) keys, descending ----------------
template<int N, int K>
__global__ __launch_bounds__(1024) void k_topk(const double* __restrict__ vals, int* __restrict__ outIdx) {
    __shared__ unsigned long long keys[N];
    int b = blockIdx.x, tid = threadIdx.x;
    for (int i = tid; i < N; i += 1024) {
        float v = (float)vals[(size_t)b * N + i];
        unsigned int u = __float_as_uint(v);
        u = (u & 0x80000000u) ? ~u : (u | 0x80000000u);
        keys[i] = ((unsigned long long)u << 32) | (unsigned int)(~i);
    }
    __syncthreads();
    for (int k = 2; k <= N; k <<= 1)
        for (int j = k >> 1; j > 0; j >>= 1) {
            for (int i = tid; i < N; i += 1024) {
                int l = i ^ j;
                if (l > i) {
                    unsigned long long a = keys[i], c = keys[l];
                    bool up = ((i & k) == 0);
                    if ((a < c) == up) { keys[i] = c; keys[l] = a; }
                }
            }
            __syncthreads();
        }
    for (int i = tid; i < K; i += 1024)
        outIdx[(size_t)b * K + i] = (int)(~(unsigned int)keys[i]);
}

// ---------------- gathers ----------------
// grid (NPROC, nb). Writes Wh/Wl with per-batch stride wstride.
__global__ void k_gatherW(const float* __restrict__ pw, const int* __restrict__ iidx,
                          _Float16* __restrict__ Wh, _Float16* __restrict__ Wl,
                          int b_base, size_t wstride) {
    int p = blockIdx.x;
    int b = b_base + blockIdx.y;
    const float* row = pw + (size_t)p * NIN;
    const int* ix = iidx + (size_t)b * KIN;
    _Float16* wh = Wh + (size_t)blockIdx.y * wstride + (size_t)p * KIN;
    _Float16* wl = Wl + (size_t)blockIdx.y * wstride + (size_t)p * KIN;
    for (int j = threadIdx.x; j < KIN; j += 256) {
        float w = row[ix[j]];
        _Float16 h = (_Float16)w;
        wh[j] = h;
        wl[j] = (_Float16)(w - (float)h);
    }
}

__global__ void k_gatherSP(const _Float16* __restrict__ acts16, const int* __restrict__ pidx,
                           _Float16* __restrict__ sp) {
    int s = blockIdx.x, b = blockIdx.y;
    const _Float16* arow = acts16 + ((size_t)b * S_ + s) * NPROC;
    _Float16* orow = sp + ((size_t)b * S_ + s) * KPROC;
    const int* pi = pidx + (size_t)b * KPROC;
    for (int k = threadIdx.x; k < KPROC; k += 256) orow[k] = arow[pi[k]];
}

__global__ void k_gatherWoT(const _Float16* __restrict__ pout16, const int* __restrict__ pidx,
                            _Float16* __restrict__ woT) {
    __shared__ _Float16 t[64][65];
    int k0 = blockIdx.x * 64, d0 = blockIdx.y * 64, b = blockIdx.z;
    const int* pi = pidx + (size_t)b * KPROC;
    for (int i = threadIdx.x; i < 4096; i += 256) {
        int kk = i >> 6, dd = i & 63;
        t[kk][dd] = pout16[(size_t)pi[k0 + kk] * D_ + d0 + dd];
    }
    __syncthreads();
    for (int i = threadIdx.x; i < 4096; i += 256) {
        int dd = i >> 6, kk = i & 63;
        woT[((size_t)b * D_ + d0 + dd) * KPROC + k0 + kk] = t[kk][dd];
    }
}

// ---------------- stage D: sel_acts = gelu(x16 * (ph+pl)^T) on gathered pattern rows ----------------
__global__ __launch_bounds__(256) void k_gemmD(
    const _Float16* __restrict__ x16, const _Float16* __restrict__ ph, const _Float16* __restrict__ pl,
    const int* __restrict__ iidx, _Float16* __restrict__ a16)
{
    const int b = blockIdx.z;
    const int m0 = blockIdx.x * 128, n0 = blockIdx.y * 128;
    __shared__ _Float16 tA[4096], tBh[4096], tBl[4096];
    const int tid = threadIdx.x, lane = tid & 63;
    const int wave = tid >> 6, wrow = wave >> 1, wcol = wave & 1;
    const int srow = tid >> 2, spart = tid & 3;

    const _Float16* as0 = x16 + ((size_t)b * S_ + m0 + srow) * D_ + spart * 8;
    const _Float16* as1 = as0 + (size_t)64 * D_;
    int r0 = iidx[(size_t)b * KIN + n0 + srow];
    int r1 = iidx[(size_t)b * KIN + n0 + srow + 64];
    const _Float16* bh0 = ph + (size_t)r0 * D_ + spart * 8;
    const _Float16* bh1 = ph + (size_t)r1 * D_ + spart * 8;
    const _Float16* bl0 = pl + (size_t)r0 * D_ + spart * 8;
    const _Float16* bl1 = pl + (size_t)r1 * D_ + spart * 8;

    v4f acc[4][4];
    v4f z = {0.f, 0.f, 0.f, 0.f};
#pragma unroll
    for (int i = 0; i < 4; i++)
#pragma unroll
        for (int j = 0; j < 4; j++) acc[i][j] = z;

    const int aoff = (wrow * 64 + (lane & 15)) * 32 + (lane >> 4) * 8;
    const int boff = (wcol * 64 + (lane & 15)) * 32 + (lane >> 4) * 8;

    for (int kt = 0; kt < D_; kt += 32) {
        __syncthreads();
        cp16(&tA[tid * 8], as0 + kt);
        cp16(&tA[2048 + tid * 8], as1 + kt);
        cp16(&tBh[tid * 8], bh0 + kt);
        cp16(&tBh[2048 + tid * 8], bh1 + kt);
        cp16(&tBl[tid * 8], bl0 + kt);
        cp16(&tBl[2048 + tid * 8], bl1 + kt);
        asm volatile("s_waitcnt vmcnt(0)" ::: "memory");
        __syncthreads();
        v8h af[4], fh[4], fl[4];
#pragma unroll
        for (int i = 0; i < 4; i++) af[i] = *(const v8h*)&tA[aoff + i * 512];
#pragma unroll
        for (int j = 0; j < 4; j++) {
            fh[j] = *(const v8h*)&tBh[boff + j * 512];
            fl[j] = *(const v8h*)&tBl[boff + j * 512];
        }
#pragma unroll
        for (int i = 0; i < 4; i++)
#pragma unroll
            for (int j = 0; j < 4; j++) {
                acc[i][j] = __builtin_amdgcn_mfma_f32_16x16x32_f16(af[i], fh[j], acc[i][j], 0, 0, 0);
                acc[i][j] = __builtin_amdgcn_mfma_f32_16x16x32_f16(af[i], fl[j], acc[i][j], 0, 0, 0);
            }
    }
    const int rbase = m0 + wrow * 64 + ((lane >> 4) << 2);
    const int cbase = n0 + wcol * 64 + (lane & 15);
#pragma unroll
    for (int i = 0; i < 4; i++)
#pragma unroll
        for (int j = 0; j < 4; j++)
#pragma unroll
            for (int r = 0; r < 4; r++) {
                float gv = geluf(acc[i][j][r]);
                a16[((size_t)b * S_ + rbase + i * 16 + r) * (size_t)KIN + cbase + j * 16] = (_Float16)gv;
            }
}

// ---------------- stage E: proc_acts = gelu(a16 * (Wh+Wl)^T), scores += column sums ----------------
// b = b_base + blockIdx.z; Wh/Wl indexed with per-batch stride wstride (0 for thin path).
__global__ __launch_bounds__(256) void k_gemmE(
    const _Float16* __restrict__ a16, const _Float16* __restrict__ Wh, const _Float16* __restrict__ Wl,
    _Float16* __restrict__ acts16, double* __restrict__ scores, int b_base, size_t wstride)
{
    const int b = b_base + blockIdx.z;
    const int m0 = blockIdx.x * 128, n0 = blockIdx.y * 128;
    __shared__ _Float16 tA[4096], tBh[4096], tBl[4096];
    const int tid = threadIdx.x, lane = tid & 63;
    const int wave = tid >> 6, wrow = wave >> 1, wcol = wave & 1;
    const int srow = tid >> 2, spart = tid & 3;

    const _Float16* as0 = a16 + ((size_t)b * S_ + m0 + srow) * (size_t)KIN + spart * 8;
    const _Float16* as1 = as0 + (size_t)64 * KIN;
    const _Float16* whB = Wh + (size_t)blockIdx.z * wstride;
    const _Float16* wlB = Wl + (size_t)blockIdx.z * wstride;
    const _Float16* bh0 = whB + (size_t)(n0 + srow) * KIN + spart * 8;
    const _Float16* bh1 = bh0 + (size_t)64 * KIN;
    const _Float16* bl0 = wlB + (size_t)(n0 + srow) * KIN + spart * 8;
    const _Float16* bl1 = bl0 + (size_t)64 * KIN;

    v4f acc[4][4];
    v4f z = {0.f, 0.f, 0.f, 0.f};
#pragma unroll
    for (int i = 0; i < 4; i++)
#pragma unroll
        for (int j = 0; j < 4; j++) acc[i][j] = z;

    const int aoff = (wrow * 64 + (lane & 15)) * 32 + (lane >> 4) * 8;
    const int boff = (wcol * 64 + (lane & 15)) * 32 + (lane >> 4) * 8;

    for (int kt = 0; kt < KIN; kt += 32) {
        __syncthreads();
        cp16(&tA[tid * 8], as0 + kt);
        cp16(&tA[2048 + tid * 8], as1 + kt);
        cp16(&tBh[tid * 8], bh0 + kt);
        cp16(&tBh[2048 + tid * 8], bh1 + kt);
        cp16(&tBl[tid * 8], bl0 + kt);
        cp16(&tBl[2048 + tid * 8], bl1 + kt);
        asm volatile("s_waitcnt vmcnt(0)" ::: "memory");
        __syncthreads();
        v8h af[4], fh[4], fl[4];
#pragma unroll
        for (int i = 0; i < 4; i++) af[i] = *(const v8h*)&tA[aoff + i * 512];
#pragma unroll
        for (int j = 0; j < 4; j++) {
            fh[j] = *(const v8h*)&tBh[boff + j * 512];
            fl[j] = *(const v8h*)&tBl[boff + j * 512];
        }
#pragma unroll
        for (int i = 0; i < 4; i++)
#pragma unroll
            for (int j = 0; j < 4; j++) {
                acc[i][j] = __builtin_amdgcn_mfma_f32_16x16x32_f16(af[i], fh[j], acc[i][j], 0, 0, 0);
                acc[i][j] = __builtin_amdgcn_mfma_f32_16x16x32_f16(af[i], fl[j], acc[i][j], 0, 0, 0);
            }
    }
    const int rbase = m0 + wrow * 64 + ((lane >> 4) << 2);
    const int cbase = n0 + wcol * 64 + (lane & 15);
    float psum[4] = {0.f, 0.f, 0.f, 0.f};
#pragma unroll
    for (int i = 0; i < 4; i++)
#pragma unroll
        for (int j = 0; j < 4; j++)
#pragma unroll
            for (int r = 0; r < 4; r++) {
                float gv = geluf(acc[i][j][r]);
                acts16[((size_t)b * S_ + rbase + i * 16 + r) * (size_t)NPROC + cbase + j * 16] = (_Float16)gv;
                psum[j] += gv;
            }
#pragma unroll
    for (int j = 0; j < 4; j++) {
        float s = psum[j];
        s += __shfl_xor(s, 16, 64);
        s += __shfl_xor(s, 32, 64);
        if ((lane >> 4) == 0)
            atomicAdd(&scores[(size_t)b * NPROC + cbase + j * 16], (double)s);
    }
}

// ---------------- stage F: out = sp * woT^T (plain f16) ----------------
__global__ __launch_bounds__(256) void k_gemmF(
    const _Float16* __restrict__ sp, const _Float16* __restrict__ woT, float* __restrict__ out)
{
    const int b = blockIdx.z;
    const int m0 = blockIdx.x * 128, n0 = blockIdx.y * 128;
    __shared__ _Float16 tA[4096], tB[4096];
    const int tid = threadIdx.x, lane = tid & 63;
    const int wave = tid >> 6, wrow = wave >> 1, wcol = wave & 1;
    const int srow = tid >> 2, spart = tid & 3;

    const _Float16* as0 = sp + ((size_t)b * S_ + m0 + srow) * (size_t)KPROC + spart * 8;
    const _Float16* as1 = as0 + (size_t)64 * KPROC;
    const _Float16* bs0 = woT + ((size_t)b * D_ + n0 + srow) * (size_t)KPROC + spart * 8;
    const _Float16* bs1 = bs0 + (size_t)64 * KPROC;

    v4f acc[4][4];
    v4f z = {0.f, 0.f, 0.f, 0.f};
#pragma unroll
    for (int i = 0; i < 4; i++)
#pragma unroll
        for (int j = 0; j < 4; j++) acc[i][j] = z;

    const int aoff = (wrow * 64 + (lane & 15)) * 32 + (lane >> 4) * 8;
    const int boff = (wcol * 64 + (lane & 15)) * 32 + (lane >> 4) * 8;

    for (int kt = 0; kt < KPROC; kt += 32) {
        __syncthreads();
        cp16(&tA[tid * 8], as0 + kt);
        cp16(&tA[2048 + tid * 8], as1 + kt);
        cp16(&tB[tid * 8], bs0 + kt);
        cp16(&tB[2048 + tid * 8], bs1 + kt);
        asm volatile("s_waitcnt vmcnt(0)" ::: "memory");
        __syncthreads();
        v8h af[4], bf[4];
#pragma unroll
        for (int i = 0; i < 4; i++) af[i] = *(const v8h*)&tA[aoff + i * 512];
#pragma unroll
        for (int j = 0; j < 4; j++) bf[j] = *(const v8h*)&tB[boff + j * 512];
#pragma unroll
        for (int i = 0; i < 4; i++)
#pragma unroll
            for (int j = 0; j < 4; j++)
                acc[i][j] = __builtin_amdgcn_mfma_f32_16x16x32_f16(af[i], bf[j], acc[i][j], 0, 0, 0);
    }
    const int rbase = m0 + wrow * 64 + ((lane >> 4) << 2);
    const int cbase = n0 + wcol * 64 + (lane & 15);
#pragma unroll
    for (int i = 0; i < 4; i++)
#pragma unroll
        for (int j = 0; j < 4; j++)
#pragma unroll
            for (int r = 0; r < 4; r++)
                out[((size_t)b * S_ + rbase + i * 16 + r) * (size_t)D_ + cbase + j * 16] = acc[i][j][r];
}

// ---------------- host ----------------
extern "C" void kernel_launch(void* const* d_in, const int* in_sizes, int n_in,
                              void* d_out, int out_size, void* d_ws, size_t ws_size,
                              hipStream_t stream) {
    const float* x    = (const float*)d_in[0];
    const float* W1   = (const float*)d_in[1];
    const float* b1   = (const float*)d_in[2];
    const float* lng  = (const float*)d_in[3];
    const float* lnb  = (const float*)d_in[4];
    const float* W2   = (const float*)d_in[5];
    const float* b2   = (const float*)d_in[6];
    const float* keys = (const float*)d_in[7];
    const float* patt = (const float*)d_in[8];
    const float* pw   = (const float*)d_in[9];
    const float* pout = (const float*)d_in[10];
    (void)in_sizes; (void)n_in; (void)out_size;

    char* w = (char*)d_ws;
    size_t off = 0;
    auto alloc = [&](size_t bytes) -> void* {
        void* p = w + off;
        off += (bytes + 255) & ~(size_t)255;
        return p;
    };
    double* gc64   = (double*)alloc((size_t)B_ * D_ * 8);
    float*  pmax   = (float*) alloc((size_t)B_ * 16 * D_ * 4);
    double* logits = (double*)alloc((size_t)B_ * NIN * 8);
    double* scores = (double*)alloc((size_t)B_ * NPROC * 8);
    double* hpre   = (double*)alloc((size_t)B_ * DR2 * 8);
    double* qs     = (double*)alloc((size_t)B_ * DR * 8);
    int*    iidx   = (int*)   alloc((size_t)B_ * KIN * 4);
    int*    pidx   = (int*)   alloc((size_t)B_ * KPROC * 4);
    _Float16* a16    = (_Float16*)alloc((size_t)B_ * S_ * KIN * 2);    // 67 MB
    _Float16* acts16 = (_Float16*)alloc((size_t)B_ * S_ * NPROC * 2);  // 67 MB
    _Float16* pout16 = (_Float16*)alloc((size_t)NPROC * D_ * 2);       // 8.4 MB
    // union region (67.1 MB): phase1 {x16, ph, pl}; thin-phase2 {Wh, Wl}; phase3 {sp, woT}
    char* u1 = (char*)alloc((size_t)67108864);
    _Float16* x16 = (_Float16*)u1;
    _Float16* ph  = (_Float16*)(u1 + 16777216);
    _Float16* pl  = (_Float16*)(u1 + 33554432);
    _Float16* WhT = (_Float16*)u1;               // thin path, one batch
    _Float16* WlT = (_Float16*)(u1 + 33554432);
    _Float16* sp  = (_Float16*)u1;
    _Float16* woT = (_Float16*)(u1 + 33554432);

    // fat path: all-batch gathered W (hi/lo), 2 x 134.2 MB
    const size_t WSTRIDE = (size_t)NPROC * KIN;          // elements per batch
    size_t off_before_fat = off;
    _Float16* WhA = (_Float16*)alloc((size_t)B_ * WSTRIDE * 2);
    _Float16* WlA = (_Float16*)alloc((size_t)B_ * WSTRIDE * 2);
    bool fat = (off <= ws_size);
    if (!fat) off = off_before_fat;

    hipMemsetAsync(scores, 0, (size_t)B_ * NPROC * 8, stream);

    k_conv_x16 <<<dim3((B_ * S_ * D_ / 4 + 255) / 256), 256, 0, stream>>>(x, x16, B_ * S_ * D_ / 4);
    k_conv_split<<<dim3((NIN * D_ + 255) / 256), 256, 0, stream>>>(patt, ph, pl, NIN * D_);
    k_conv_x16 <<<dim3((NPROC * D_ / 4 + 255) / 256), 256, 0, stream>>>(pout, pout16, NPROC * D_ / 4);

    k_max1<<<dim3(4, 16, 4), 256, 0, stream>>>(x, pmax);
    k_max2<<<dim3(4, 4), 256, 0, stream>>>(pmax, gc64);
    k_router1<<<dim3(128, 4), 256, 0, stream>>>(gc64, W1, b1, hpre);
    k_router2<<<dim3(4), 512, 0, stream>>>(hpre, lng, lnb, W2, b2, qs);
    k_router3<<<dim3(2048, 4), 256, 0, stream>>>(qs, keys, logits);
    k_topk<NIN, KIN><<<dim3(4), 1024, 0, stream>>>(logits, iidx);

    if (fat) {
        // gather all 4 batches at once (pw read once, L3-resident), then one big E launch
        k_gatherW<<<dim3(NPROC, 4), 256, 0, stream>>>(pw, iidx, WhA, WlA, 0, WSTRIDE);
        k_gemmD<<<dim3(16, 32, 4), 256, 0, stream>>>(x16, ph, pl, iidx, a16);
        k_gemmE<<<dim3(16, 32, 4), 256, 0, stream>>>(a16, WhA, WlA, acts16, scores, 0, WSTRIDE);
    } else {
        k_gemmD<<<dim3(16, 32, 4), 256, 0, stream>>>(x16, ph, pl, iidx, a16);
        for (int b = 0; b < 4; b++) {
            k_gatherW<<<dim3(NPROC, 1), 256, 0, stream>>>(pw, iidx, WhT, WlT, b, 0);
            k_gemmE<<<dim3(16, 32, 1), 256, 0, stream>>>(a16, WhT, WlT, acts16, scores, b, 0);
        }
    }

    k_topk<NPROC, KPROC><<<dim3(4), 1024, 0, stream>>>(scores, pidx);
    k_gatherSP<<<dim3(S_, 4), 256, 0, stream>>>(acts16, pidx, sp);
    k_gatherWoT<<<dim3(KPROC / 64, D_ / 64, 4), 256, 0, stream>>>(pout16, pidx, woT);
    k_gemmF<<<dim3(16, 8, 4), 256, 0, stream>>>(sp, woT, (float*)d_out);
}

// Round 3
// 1666.072 us; speedup vs baseline: 1.2625x; 1.0808x over previous
//
#include <hip/hip_runtime.h>
#include <cstdint>

#define B_    4
#define S_    2048
#define D_    1024
#define NIN   8192
#define NPROC 4096
#define DR    256
#define DR2   512
#define KIN   4096
#define KPROC 2048

typedef _Float16 v8h __attribute__((ext_vector_type(8)));
typedef _Float16 v4h __attribute__((ext_vector_type(4)));
typedef float    v4f __attribute__((ext_vector_type(4)));

__device__ __forceinline__ float geluf(float v) {
    return 0.5f * v * (1.0f + erff(v * 0.70710678f));
}

// async global->LDS, 16B per lane. LDS dest semantics: wave-uniform base + lane*16.
__device__ __forceinline__ void cp16(void* lds, const void* g) {
    __builtin_amdgcn_global_load_lds(
        (const __attribute__((address_space(1))) unsigned int*)g,
        (__attribute__((address_space(3))) unsigned int*)lds, 16, 0, 0);
}

// ---------------- converts ----------------
__global__ void k_conv_x16(const float* __restrict__ x, _Float16* __restrict__ x16, int n4) {
    int i = blockIdx.x * 256 + threadIdx.x;
    if (i < n4) {
        float4 v = ((const float4*)x)[i];
        v4h h = { (_Float16)v.x, (_Float16)v.y, (_Float16)v.z, (_Float16)v.w };
        ((v4h*)x16)[i] = h;
    }
}

__global__ void k_conv_split(const float* __restrict__ p, _Float16* __restrict__ ph,
                             _Float16* __restrict__ pl, int n) {
    int i = blockIdx.x * 256 + threadIdx.x;
    if (i < n) {
        float v = p[i];
        _Float16 h = (_Float16)v;
        ph[i] = h;
        pl[i] = (_Float16)(v - (float)h);
    }
}

// ---------------- gc = max over s ----------------
__global__ void k_max1(const float* __restrict__ x, float* __restrict__ pmax) {
    int d = blockIdx.x * 256 + threadIdx.x;   // grid.x = 4
    int chunk = blockIdx.y;                   // 16
    int b = blockIdx.z;                       // 4
    const float* base = x + ((size_t)b * S_ + chunk * 128) * D_ + d;
    float m = -3.4e38f;
    for (int s = 0; s < 128; s++) m = fmaxf(m, base[(size_t)s * D_]);
    pmax[((size_t)b * 16 + chunk) * D_ + d] = m;
}

__global__ void k_max2(const float* __restrict__ pmax, double* __restrict__ gc64) {
    int d = blockIdx.x * 256 + threadIdx.x;   // grid.x = 4
    int b = blockIdx.y;
    float m = -3.4e38f;
    for (int c = 0; c < 16; c++) m = fmaxf(m, pmax[((size_t)b * 16 + c) * D_ + d]);
    gc64[(size_t)b * D_ + d] = (double)m;
}

// ---------------- router stage 1: hpre[b][j] = gelu(gc . W1_j + b1_j), fp64 ----------------
__global__ __launch_bounds__(256) void k_router1(
    const double* __restrict__ gc64, const float* __restrict__ W1, const float* __restrict__ b1,
    double* __restrict__ hpre)
{
    int wave = threadIdx.x >> 6, lane = threadIdx.x & 63;
    int j = blockIdx.x * 4 + wave;
    int b = blockIdx.y;
    const double* g = gc64 + (size_t)b * D_;
    const float* w = W1 + (size_t)j * D_;
    double acc = 0.0;
    for (int d = lane; d < D_; d += 64) acc += g[d] * (double)w[d];
#pragma unroll
    for (int o = 32; o > 0; o >>= 1) acc += __shfl_xor(acc, o, 64);
    if (lane == 0) {
        double z = acc + (double)b1[j];
        hpre[(size_t)b * DR2 + j] = 0.5 * z * (1.0 + erf(z * 0.7071067811865475244));
    }
}

// ---------------- router stage 2: LN + query, fp64. one block per batch ----------------
__global__ __launch_bounds__(512) void k_router2(
    const double* __restrict__ hpre, const float* __restrict__ lng, const float* __restrict__ lnb,
    const float* __restrict__ W2, const float* __restrict__ b2, double* __restrict__ qs)
{
    __shared__ double sh[DR2];
    __shared__ double red[DR2];
    int b = blockIdx.x, j = threadIdx.x;
    double ge = hpre[(size_t)b * DR2 + j];
    sh[j] = ge; red[j] = ge;
    __syncthreads();
    for (int s = 256; s > 0; s >>= 1) { if (j < s) red[j] += red[j + s]; __syncthreads(); }
    double mu = red[0] / 512.0;
    __syncthreads();
    double dv = ge - mu;
    red[j] = dv * dv;
    __syncthreads();
    for (int s = 256; s > 0; s >>= 1) { if (j < s) red[j] += red[j + s]; __syncthreads(); }
    double rs = 1.0 / sqrt(red[0] / 512.0 + 1e-5);
    __syncthreads();
    sh[j] = dv * rs * (double)lng[j] + (double)lnb[j];
    __syncthreads();
    if (j < DR) {
        double q = (double)b2[j];
        const float* w2r = W2 + (size_t)j * DR2;
        for (int t = 0; t < DR2; t++) q += sh[t] * (double)w2r[t];
        qs[(size_t)b * DR + j] = q;
    }
}

// ---------------- router stage 3: logits, fp64. one wave per (b,n). grid (2048,4) ----------------
__global__ __launch_bounds__(256) void k_router3(
    const double* __restrict__ qs, const float* __restrict__ keys, double* __restrict__ logits)
{
    int wave = threadIdx.x >> 6, lane = threadIdx.x & 63;
    int n = blockIdx.x * 4 + wave;
    int b = blockIdx.y;
    const double* q = qs + (size_t)b * DR;
    const float* kr = keys + (size_t)n * DR;
    double acc = 0.0;
#pragma unroll
    for (int t = 0; t < 4; t++) {
        int d = lane + t * 64;
        acc += q[d] * (double)kr[d];
    }
#pragma unroll
    for (int o = 32; o > 0; o >>= 1) acc += __shfl_xor(acc, o, 64);
    if (lane == 0) logits[(size_t)b * NIN + n] = acc * 0.0625;  // / sqrt(256)
}

// ---------------- top-k: in-LDS bitonic sort of (value,~idx) keys, descending ----------------
template<int N, int K>
__global__ __launch_bounds__(1024) void k_topk(const double* __restrict__ vals, int* __restrict__ outIdx) {
    __shared__ unsigned long long keys[N];
    int b = blockIdx.x, tid = threadIdx.x;
    for (int i = tid; i < N; i += 1024) {
        float v = (float)vals[(size_t)b * N + i];
        unsigned int u = __float_as_uint(v);
        u = (u & 0x80000000u) ? ~u : (u | 0x80000000u);
        keys[i] = ((unsigned long long)u << 32) | (unsigned int)(~i);
    }
    __syncthreads();
    for (int k = 2; k <= N; k <<= 1)
        for (int j = k >> 1; j > 0; j >>= 1) {
            for (int i = tid; i < N; i += 1024) {
                int l = i ^ j;
                if (l > i) {
                    unsigned long long a = keys[i], c = keys[l];
                    bool up = ((i & k) == 0);
                    if ((a < c) == up) { keys[i] = c; keys[l] = a; }
                }
            }
            __syncthreads();
        }
    for (int i = tid; i < K; i += 1024)
        outIdx[(size_t)b * K + i] = (int)(~(unsigned int)keys[i]);
}

// ---------------- gathers ----------------
__global__ void k_gatherW(const float* __restrict__ pw, const int* __restrict__ iidx,
                          _Float16* __restrict__ Wh, _Float16* __restrict__ Wl,
                          int b_base, size_t wstride) {
    int p = blockIdx.x;
    int b = b_base + blockIdx.y;
    const float* row = pw + (size_t)p * NIN;
    const int* ix = iidx + (size_t)b * KIN;
    _Float16* wh = Wh + (size_t)blockIdx.y * wstride + (size_t)p * KIN;
    _Float16* wl = Wl + (size_t)blockIdx.y * wstride + (size_t)p * KIN;
    for (int j = threadIdx.x; j < KIN; j += 256) {
        float w = row[ix[j]];
        _Float16 h = (_Float16)w;
        wh[j] = h;
        wl[j] = (_Float16)(w - (float)h);
    }
}

__global__ void k_gatherSP(const _Float16* __restrict__ acts16, const int* __restrict__ pidx,
                           _Float16* __restrict__ sp) {
    int s = blockIdx.x, b = blockIdx.y;
    const _Float16* arow = acts16 + ((size_t)b * S_ + s) * NPROC;
    _Float16* orow = sp + ((size_t)b * S_ + s) * KPROC;
    const int* pi = pidx + (size_t)b * KPROC;
    for (int k = threadIdx.x; k < KPROC; k += 256) orow[k] = arow[pi[k]];
}

__global__ void k_gatherWoT(const _Float16* __restrict__ pout16, const int* __restrict__ pidx,
                            _Float16* __restrict__ woT) {
    __shared__ _Float16 t[64][65];
    int k0 = blockIdx.x * 64, d0 = blockIdx.y * 64, b = blockIdx.z;
    const int* pi = pidx + (size_t)b * KPROC;
    for (int i = threadIdx.x; i < 4096; i += 256) {
        int kk = i >> 6, dd = i & 63;
        t[kk][dd] = pout16[(size_t)pi[k0 + kk] * D_ + d0 + dd];
    }
    __syncthreads();
    for (int i = threadIdx.x; i < 4096; i += 256) {
        int dd = i >> 6, kk = i & 63;
        woT[((size_t)b * D_ + d0 + dd) * KPROC + k0 + kk] = t[kk][dd];
    }
}

// XOR-swizzle: LDS physical chunk p holds global chunk p ^ ((row>>1)&3).
// Writer permutes the global source per lane (LDS dest must stay base+lane*16);
// reader XORs its quad index. Spreads the 16-lane row-walk over 8 bank groups
// (2-way = free) instead of 2 (8-way).

// ---------------- stage D: sel_acts = gelu(x16 * (ph+pl)^T) on gathered pattern rows ----------------
__global__ __launch_bounds__(256, 3) void k_gemmD(
    const _Float16* __restrict__ x16, const _Float16* __restrict__ ph, const _Float16* __restrict__ pl,
    const int* __restrict__ iidx, _Float16* __restrict__ a16)
{
    const int b = blockIdx.z;
    const int m0 = blockIdx.x * 128, n0 = blockIdx.y * 128;
    __shared__ _Float16 tA[4096], tBh[4096], tBl[4096];
    const int tid = threadIdx.x, lane = tid & 63;
    const int wave = tid >> 6, wrow = wave >> 1, wcol = wave & 1;
    const int srow = tid >> 2, spart = tid & 3;
    const int spe = spart ^ ((srow >> 1) & 3);   // swizzled source chunk

    const _Float16* as0 = x16 + ((size_t)b * S_ + m0 + srow) * D_ + spe * 8;
    const _Float16* as1 = as0 + (size_t)64 * D_;
    int r0 = iidx[(size_t)b * KIN + n0 + srow];
    int r1 = iidx[(size_t)b * KIN + n0 + srow + 64];
    const _Float16* bh0 = ph + (size_t)r0 * D_ + spe * 8;
    const _Float16* bh1 = ph + (size_t)r1 * D_ + spe * 8;
    const _Float16* bl0 = pl + (size_t)r0 * D_ + spe * 8;
    const _Float16* bl1 = pl + (size_t)r1 * D_ + spe * 8;

    v4f acc[4][4];
    v4f z = {0.f, 0.f, 0.f, 0.f};
#pragma unroll
    for (int i = 0; i < 4; i++)
#pragma unroll
        for (int j = 0; j < 4; j++) acc[i][j] = z;

    const int swz = ((lane & 15) >> 1) & 3;
    const int aoff = (wrow * 64 + (lane & 15)) * 32 + ((lane >> 4) ^ swz) * 8;
    const int boff = (wcol * 64 + (lane & 15)) * 32 + ((lane >> 4) ^ swz) * 8;

    for (int kt = 0; kt < D_; kt += 32) {
        __syncthreads();
        cp16(&tA[tid * 8], as0 + kt);
        cp16(&tA[2048 + tid * 8], as1 + kt);
        cp16(&tBh[tid * 8], bh0 + kt);
        cp16(&tBh[2048 + tid * 8], bh1 + kt);
        cp16(&tBl[tid * 8], bl0 + kt);
        cp16(&tBl[2048 + tid * 8], bl1 + kt);
        asm volatile("s_waitcnt vmcnt(0)" ::: "memory");
        __syncthreads();
        v8h af[4], fh[4], fl[4];
#pragma unroll
        for (int i = 0; i < 4; i++) af[i] = *(const v8h*)&tA[aoff + i * 512];
#pragma unroll
        for (int j = 0; j < 4; j++) {
            fh[j] = *(const v8h*)&tBh[boff + j * 512];
            fl[j] = *(const v8h*)&tBl[boff + j * 512];
        }
#pragma unroll
        for (int i = 0; i < 4; i++)
#pragma unroll
            for (int j = 0; j < 4; j++) {
                acc[i][j] = __builtin_amdgcn_mfma_f32_16x16x32_f16(af[i], fh[j], acc[i][j], 0, 0, 0);
                acc[i][j] = __builtin_amdgcn_mfma_f32_16x16x32_f16(af[i], fl[j], acc[i][j], 0, 0, 0);
            }
    }
    const int rbase = m0 + wrow * 64 + ((lane >> 4) << 2);
    const int cbase = n0 + wcol * 64 + (lane & 15);
#pragma unroll
    for (int i = 0; i < 4; i++)
#pragma unroll
        for (int j = 0; j < 4; j++)
#pragma unroll
            for (int r = 0; r < 4; r++) {
                float gv = geluf(acc[i][j][r]);
                a16[((size_t)b * S_ + rbase + i * 16 + r) * (size_t)KIN + cbase + j * 16] = (_Float16)gv;
            }
}

// ---------------- stage E: proc_acts = gelu(a16 * (Wh+Wl)^T), scores += column sums ----------------
__global__ __launch_bounds__(256, 3) void k_gemmE(
    const _Float16* __restrict__ a16, const _Float16* __restrict__ Wh, const _Float16* __restrict__ Wl,
    _Float16* __restrict__ acts16, double* __restrict__ scores, int b_base, size_t wstride)
{
    const int b = b_base + blockIdx.z;
    const int m0 = blockIdx.x * 128, n0 = blockIdx.y * 128;
    __shared__ _Float16 tA[4096], tBh[4096], tBl[4096];
    const int tid = threadIdx.x, lane = tid & 63;
    const int wave = tid >> 6, wrow = wave >> 1, wcol = wave & 1;
    const int srow = tid >> 2, spart = tid & 3;
    const int spe = spart ^ ((srow >> 1) & 3);

    const _Float16* as0 = a16 + ((size_t)b * S_ + m0 + srow) * (size_t)KIN + spe * 8;
    const _Float16* as1 = as0 + (size_t)64 * KIN;
    const _Float16* whB = Wh + (size_t)blockIdx.z * wstride;
    const _Float16* wlB = Wl + (size_t)blockIdx.z * wstride;
    const _Float16* bh0 = whB + (size_t)(n0 + srow) * KIN + spe * 8;
    const _Float16* bh1 = bh0 + (size_t)64 * KIN;
    const _Float16* bl0 = wlB + (size_t)(n0 + srow) * KIN + spe * 8;
    const _Float16* bl1 = bl0 + (size_t)64 * KIN;

    v4f acc[4][4];
    v4f z = {0.f, 0.f, 0.f, 0.f};
#pragma unroll
    for (int i = 0; i < 4; i++)
#pragma unroll
        for (int j = 0; j < 4; j++) acc[i][j] = z;

    const int swz = ((lane & 15) >> 1) & 3;
    const int aoff = (wrow * 64 + (lane & 15)) * 32 + ((lane >> 4) ^ swz) * 8;
    const int boff = (wcol * 64 + (lane & 15)) * 32 + ((lane >> 4) ^ swz) * 8;

    for (int kt = 0; kt < KIN; kt += 32) {
        __syncthreads();
        cp16(&tA[tid * 8], as0 + kt);
        cp16(&tA[2048 + tid * 8], as1 + kt);
        cp16(&tBh[tid * 8], bh0 + kt);
        cp16(&tBh[2048 + tid * 8], bh1 + kt);
        cp16(&tBl[tid * 8], bl0 + kt);
        cp16(&tBl[2048 + tid * 8], bl1 + kt);
        asm volatile("s_waitcnt vmcnt(0)" ::: "memory");
        __syncthreads();
        v8h af[4], fh[4], fl[4];
#pragma unroll
        for (int i = 0; i < 4; i++) af[i] = *(const v8h*)&tA[aoff + i * 512];
#pragma unroll
        for (int j = 0; j < 4; j++) {
            fh[j] = *(const v8h*)&tBh[boff + j * 512];
            fl[j] = *(const v8h*)&tBl[boff + j * 512];
        }
#pragma unroll
        for (int i = 0; i < 4; i++)
#pragma unroll
            for (int j = 0; j < 4; j++) {
                acc[i][j] = __builtin_amdgcn_mfma_f32_16x16x32_f16(af[i], fh[j], acc[i][j], 0, 0, 0);
                acc[i][j] = __builtin_amdgcn_mfma_f32_16x16x32_f16(af[i], fl[j], acc[i][j], 0, 0, 0);
            }
    }
    const int rbase = m0 + wrow * 64 + ((lane >> 4) << 2);
    const int cbase = n0 + wcol * 64 + (lane & 15);
    float psum[4] = {0.f, 0.f, 0.f, 0.f};
#pragma unroll
    for (int i = 0; i < 4; i++)
#pragma unroll
        for (int j = 0; j < 4; j++)
#pragma unroll
            for (int r = 0; r < 4; r++) {
                float gv = geluf(acc[i][j][r]);
                acts16[((size_t)b * S_ + rbase + i * 16 + r) * (size_t)NPROC + cbase + j * 16] = (_Float16)gv;
                psum[j] += gv;
            }
#pragma unroll
    for (int j = 0; j < 4; j++) {
        float s = psum[j];
        s += __shfl_xor(s, 16, 64);
        s += __shfl_xor(s, 32, 64);
        if ((lane >> 4) == 0)
            atomicAdd(&scores[(size_t)b * NPROC + cbase + j * 16], (double)s);
    }
}

// ---------------- stage F: out = sp * woT^T (plain f16) ----------------
__global__ __launch_bounds__(256, 3) void k_gemmF(
    const _Float16* __restrict__ sp, const _Float16* __restrict__ woT, float* __restrict__ out)
{
    const int b = blockIdx.z;
    const int m0 = blockIdx.x * 128, n0 = blockIdx.y * 128;
    __shared__ _Float16 tA[4096], tB[4096];
    const int tid = threadIdx.x, lane = tid & 63;
    const int wave = tid >> 6, wrow = wave >> 1, wcol = wave & 1;
    const int srow = tid >> 2, spart = tid & 3;
    const int spe = spart ^ ((srow >> 1) & 3);

    const _Float16* as0 = sp + ((size_t)b * S_ + m0 + srow) * (size_t)KPROC + spe * 8;
    const _Float16* as1 = as0 + (size_t)64 * KPROC;
    const _Float16* bs0 = woT + ((size_t)b * D_ + n0 + srow) * (size_t)KPROC + spe * 8;
    const _Float16* bs1 = bs0 + (size_t)64 * KPROC;

    v4f acc[4][4];
    v4f z = {0.f, 0.f, 0.f, 0.f};
#pragma unroll
    for (int i = 0; i < 4; i++)
#pragma unroll
        for (int j = 0; j < 4; j++) acc[i][j] = z;

    const int swz = ((lane & 15) >> 1) & 3;
    const int aoff = (wrow * 64 + (lane & 15)) * 32 + ((lane >> 4) ^ swz) * 8;
    const int boff = (wcol * 64 + (lane & 15)) * 32 + ((lane >> 4) ^ swz) * 8;

    for (int kt = 0; kt < KPROC; kt += 32) {
        __syncthreads();
        cp16(&tA[tid * 8], as0 + kt);
        cp16(&tA[2048 + tid * 8], as1 + kt);
        cp16(&tB[tid * 8], bs0 + kt);
        cp16(&tB[2048 + tid * 8], bs1 + kt);
        asm volatile("s_waitcnt vmcnt(0)" ::: "memory");
        __syncthreads();
        v8h af[4], bf[4];
#pragma unroll
        for (int i = 0; i < 4; i++) af[i] = *(const v8h*)&tA[aoff + i * 512];
#pragma unroll
        for (int j = 0; j < 4; j++) bf[j] = *(const v8h*)&tB[boff + j * 512];
#pragma unroll
        for (int i = 0; i < 4; i++)
#pragma unroll
            for (int j = 0; j < 4; j++)
                acc[i][j] = __builtin_amdgcn_mfma_f32_16x16x32_f16(af[i], bf[j], acc[i][j], 0, 0, 0);
    }
    const int rbase = m0 + wrow * 64 + ((lane >> 4) << 2);
    const int cbase = n0 + wcol * 64 + (lane & 15);
#pragma unroll
    for (int i = 0; i < 4; i++)
#pragma unroll
        for (int j = 0; j < 4; j++)
#pragma unroll
            for (int r = 0; r < 4; r++)
                out[((size_t)b * S_ + rbase + i * 16 + r) * (size_t)D_ + cbase + j * 16] = acc[i][j][r];
}

// ---------------- host ----------------
extern "C" void kernel_launch(void* const* d_in, const int* in_sizes, int n_in,
                              void* d_out, int out_size, void* d_ws, size_t ws_size,
                              hipStream_t stream) {
    const float* x    = (const float*)d_in[0];
    const float* W1   = (const float*)d_in[1];
    const float* b1   = (const float*)d_in[2];
    const float* lng  = (const float*)d_in[3];
    const float* lnb  = (const float*)d_in[4];
    const float* W2   = (const float*)d_in[5];
    const float* b2   = (const float*)d_in[6];
    const float* keys = (const float*)d_in[7];
    const float* patt = (const float*)d_in[8];
    const float* pw   = (const float*)d_in[9];
    const float* pout = (const float*)d_in[10];
    (void)in_sizes; (void)n_in; (void)out_size;

    char* w = (char*)d_ws;
    size_t off = 0;
    auto alloc = [&](size_t bytes) -> void* {
        void* p = w + off;
        off += (bytes + 255) & ~(size_t)255;
        return p;
    };
    double* gc64   = (double*)alloc((size_t)B_ * D_ * 8);
    float*  pmax   = (float*) alloc((size_t)B_ * 16 * D_ * 4);
    double* logits = (double*)alloc((size_t)B_ * NIN * 8);
    double* scores = (double*)alloc((size_t)B_ * NPROC * 8);
    double* hpre   = (double*)alloc((size_t)B_ * DR2 * 8);
    double* qs     = (double*)alloc((size_t)B_ * DR * 8);
    int*    iidx   = (int*)   alloc((size_t)B_ * KIN * 4);
    int*    pidx   = (int*)   alloc((size_t)B_ * KPROC * 4);
    _Float16* a16    = (_Float16*)alloc((size_t)B_ * S_ * KIN * 2);    // 67 MB
    _Float16* acts16 = (_Float16*)alloc((size_t)B_ * S_ * NPROC * 2);  // 67 MB
    _Float16* pout16 = (_Float16*)alloc((size_t)NPROC * D_ * 2);       // 8.4 MB
    // union region (67.1 MB): phase1 {x16, ph, pl}; thin-phase2 {Wh, Wl}; phase3 {sp, woT}
    char* u1 = (char*)alloc((size_t)67108864);
    _Float16* x16 = (_Float16*)u1;
    _Float16* ph  = (_Float16*)(u1 + 16777216);
    _Float16* pl  = (_Float16*)(u1 + 33554432);
    _Float16* WhT = (_Float16*)u1;               // thin path, one batch
    _Float16* WlT = (_Float16*)(u1 + 33554432);
    _Float16* sp  = (_Float16*)u1;
    _Float16* woT = (_Float16*)(u1 + 33554432);

    // fat path: all-batch gathered W (hi/lo), 2 x 134.2 MB
    const size_t WSTRIDE = (size_t)NPROC * KIN;          // elements per batch
    size_t off_before_fat = off;
    _Float16* WhA = (_Float16*)alloc((size_t)B_ * WSTRIDE * 2);
    _Float16* WlA = (_Float16*)alloc((size_t)B_ * WSTRIDE * 2);
    bool fat = (off <= ws_size);
    if (!fat) off = off_before_fat;

    hipMemsetAsync(scores, 0, (size_t)B_ * NPROC * 8, stream);

    k_conv_x16 <<<dim3((B_ * S_ * D_ / 4 + 255) / 256), 256, 0, stream>>>(x, x16, B_ * S_ * D_ / 4);
    k_conv_split<<<dim3((NIN * D_ + 255) / 256), 256, 0, stream>>>(patt, ph, pl, NIN * D_);
    k_conv_x16 <<<dim3((NPROC * D_ / 4 + 255) / 256), 256, 0, stream>>>(pout, pout16, NPROC * D_ / 4);

    k_max1<<<dim3(4, 16, 4), 256, 0, stream>>>(x, pmax);
    k_max2<<<dim3(4, 4), 256, 0, stream>>>(pmax, gc64);
    k_router1<<<dim3(128, 4), 256, 0, stream>>>(gc64, W1, b1, hpre);
    k_router2<<<dim3(4), 512, 0, stream>>>(hpre, lng, lnb, W2, b2, qs);
    k_router3<<<dim3(2048, 4), 256, 0, stream>>>(qs, keys, logits);
    k_topk<NIN, KIN><<<dim3(4), 1024, 0, stream>>>(logits, iidx);

    if (fat) {
        // gather all 4 batches at once (pw read once, L3-resident), then one big E launch
        k_gatherW<<<dim3(NPROC, 4), 256, 0, stream>>>(pw, iidx, WhA, WlA, 0, WSTRIDE);
        k_gemmD<<<dim3(16, 32, 4), 256, 0, stream>>>(x16, ph, pl, iidx, a16);
        k_gemmE<<<dim3(16, 32, 4), 256, 0, stream>>>(a16, WhA, WlA, acts16, scores, 0, WSTRIDE);
    } else {
        k_gemmD<<<dim3(16, 32, 4), 256, 0, stream>>>(x16, ph, pl, iidx, a16);
        for (int b = 0; b < 4; b++) {
            k_gatherW<<<dim3(NPROC, 1), 256, 0, stream>>>(pw, iidx, WhT, WlT, b, 0);
            k_gemmE<<<dim3(16, 32, 1), 256, 0, stream>>>(a16, WhT, WlT, acts16, scores, b, 0);
        }
    }

    k_topk<NPROC, KPROC><<<dim3(4), 1024, 0, stream>>>(scores, pidx);
    k_gatherSP<<<dim3(S_, 4), 256, 0, stream>>>(acts16, pidx, sp);
    k_gatherWoT<<<dim3(KPROC / 64, D_ / 64, 4), 256, 0, stream>>>(pout16, pidx, woT);
    k_gemmF<<<dim3(16, 8, 4), 256, 0, stream>>>(sp, woT, (float*)d_out);
}

// Round 4
// 1662.212 us; speedup vs baseline: 1.2655x; 1.0023x over previous
//
#include <hip/hip_runtime.h>
#include <cstdint>

#define B_    4
#define S_    2048
#define D_    1024
#define NIN   8192
#define NPROC 4096
#define DR    256
#define DR2   512
#define KIN   4096
#define KPROC 2048

typedef _Float16 v8h  __attribute__((ext_vector_type(8)));
typedef _Float16 v4h  __attribute__((ext_vector_type(4)));
typedef float    v4f  __attribute__((ext_vector_type(4)));
typedef float    v16f __attribute__((ext_vector_type(16)));

__device__ __forceinline__ float geluf(float v) {
    return 0.5f * v * (1.0f + erff(v * 0.70710678f));
}

// async global->LDS, 16B per lane. LDS dest semantics: wave-uniform base + lane*16.
__device__ __forceinline__ void cp16(void* lds, const void* g) {
    __builtin_amdgcn_global_load_lds(
        (const __attribute__((address_space(1))) unsigned int*)g,
        (__attribute__((address_space(3))) unsigned int*)lds, 16, 0, 0);
}

// ---------------- converts ----------------
__global__ void k_conv_x16(const float* __restrict__ x, _Float16* __restrict__ x16, int n4) {
    int i = blockIdx.x * 256 + threadIdx.x;
    if (i < n4) {
        float4 v = ((const float4*)x)[i];
        v4h h = { (_Float16)v.x, (_Float16)v.y, (_Float16)v.z, (_Float16)v.w };
        ((v4h*)x16)[i] = h;
    }
}

__global__ void k_conv_split(const float* __restrict__ p, _Float16* __restrict__ ph,
                             _Float16* __restrict__ pl, int n) {
    int i = blockIdx.x * 256 + threadIdx.x;
    if (i < n) {
        float v = p[i];
        _Float16 h = (_Float16)v;
        ph[i] = h;
        pl[i] = (_Float16)(v - (float)h);
    }
}

// ---------------- gc = max over s ----------------
__global__ void k_max1(const float* __restrict__ x, float* __restrict__ pmax) {
    int d = blockIdx.x * 256 + threadIdx.x;
    int chunk = blockIdx.y;
    int b = blockIdx.z;
    const float* base = x + ((size_t)b * S_ + chunk * 128) * D_ + d;
    float m = -3.4e38f;
    for (int s = 0; s < 128; s++) m = fmaxf(m, base[(size_t)s * D_]);
    pmax[((size_t)b * 16 + chunk) * D_ + d] = m;
}

__global__ void k_max2(const float* __restrict__ pmax, double* __restrict__ gc64) {
    int d = blockIdx.x * 256 + threadIdx.x;
    int b = blockIdx.y;
    float m = -3.4e38f;
    for (int c = 0; c < 16; c++) m = fmaxf(m, pmax[((size_t)b * 16 + c) * D_ + d]);
    gc64[(size_t)b * D_ + d] = (double)m;
}

// ---------------- router (fp64) ----------------
__global__ __launch_bounds__(256) void k_router1(
    const double* __restrict__ gc64, const float* __restrict__ W1, const float* __restrict__ b1,
    double* __restrict__ hpre)
{
    int wave = threadIdx.x >> 6, lane = threadIdx.x & 63;
    int j = blockIdx.x * 4 + wave;
    int b = blockIdx.y;
    const double* g = gc64 + (size_t)b * D_;
    const float* w = W1 + (size_t)j * D_;
    double acc = 0.0;
    for (int d = lane; d < D_; d += 64) acc += g[d] * (double)w[d];
#pragma unroll
    for (int o = 32; o > 0; o >>= 1) acc += __shfl_xor(acc, o, 64);
    if (lane == 0) {
        double z = acc + (double)b1[j];
        hpre[(size_t)b * DR2 + j] = 0.5 * z * (1.0 + erf(z * 0.7071067811865475244));
    }
}

__global__ __launch_bounds__(512) void k_router2(
    const double* __restrict__ hpre, const float* __restrict__ lng, const float* __restrict__ lnb,
    const float* __restrict__ W2, const float* __restrict__ b2, double* __restrict__ qs)
{
    __shared__ double sh[DR2];
    __shared__ double red[DR2];
    int b = blockIdx.x, j = threadIdx.x;
    double ge = hpre[(size_t)b * DR2 + j];
    sh[j] = ge; red[j] = ge;
    __syncthreads();
    for (int s = 256; s > 0; s >>= 1) { if (j < s) red[j] += red[j + s]; __syncthreads(); }
    double mu = red[0] / 512.0;
    __syncthreads();
    double dv = ge - mu;
    red[j] = dv * dv;
    __syncthreads();
    for (int s = 256; s > 0; s >>= 1) { if (j < s) red[j] += red[j + s]; __syncthreads(); }
    double rs = 1.0 / sqrt(red[0] / 512.0 + 1e-5);
    __syncthreads();
    sh[j] = dv * rs * (double)lng[j] + (double)lnb[j];
    __syncthreads();
    if (j < DR) {
        double q = (double)b2[j];
        const float* w2r = W2 + (size_t)j * DR2;
        for (int t = 0; t < DR2; t++) q += sh[t] * (double)w2r[t];
        qs[(size_t)b * DR + j] = q;
    }
}

__global__ __launch_bounds__(256) void k_router3(
    const double* __restrict__ qs, const float* __restrict__ keys, double* __restrict__ logits)
{
    int wave = threadIdx.x >> 6, lane = threadIdx.x & 63;
    int n = blockIdx.x * 4 + wave;
    int b = blockIdx.y;
    const double* q = qs + (size_t)b * DR;
    const float* kr = keys + (size_t)n * DR;
    double acc = 0.0;
#pragma unroll
    for (int t = 0; t < 4; t++) {
        int d = lane + t * 64;
        acc += q[d] * (double)kr[d];
    }
#pragma unroll
    for (int o = 32; o > 0; o >>= 1) acc += __shfl_xor(acc, o, 64);
    if (lane == 0) logits[(size_t)b * NIN + n] = acc * 0.0625;
}

// ---------------- top-k ----------------
template<int N, int K>
__global__ __launch_bounds__(1024) void k_topk(const double* __restrict__ vals, int* __restrict__ outIdx) {
    __shared__ unsigned long long keys[N];
    int b = blockIdx.x, tid = threadIdx.x;
    for (int i = tid; i < N; i += 1024) {
        float v = (float)vals[(size_t)b * N + i];
        unsigned int u = __float_as_uint(v);
        u = (u & 0x80000000u) ? ~u : (u | 0x80000000u);
        keys[i] = ((unsigned long long)u << 32) | (unsigned int)(~i);
    }
    __syncthreads();
    for (int k = 2; k <= N; k <<= 1)
        for (int j = k >> 1; j > 0; j >>= 1) {
            for (int i = tid; i < N; i += 1024) {
                int l = i ^ j;
                if (l > i) {
                    unsigned long long a = keys[i], c = keys[l];
                    bool up = ((i & k) == 0);
                    if ((a < c) == up) { keys[i] = c; keys[l] = a; }
                }
            }
            __syncthreads();
        }
    for (int i = tid; i < K; i += 1024)
        outIdx[(size_t)b * K + i] = (int)(~(unsigned int)keys[i]);
}

// ---------------- gather bodies ----------------
__device__ __forceinline__ void dev_gatherW(const float* __restrict__ pw, const int* __restrict__ iidx,
                                            _Float16* __restrict__ Wh, _Float16* __restrict__ Wl,
                                            int p, int b, size_t bstride) {
    const float* row = pw + (size_t)p * NIN;
    const int* ix = iidx + (size_t)b * KIN;
    _Float16* wh = Wh + bstride + (size_t)p * KIN;
    _Float16* wl = Wl + bstride + (size_t)p * KIN;
    for (int j = threadIdx.x; j < KIN; j += 256) {
        float w = row[ix[j]];
        _Float16 h = (_Float16)w;
        wh[j] = h;
        wl[j] = (_Float16)(w - (float)h);
    }
}

__global__ void k_gatherSP(const _Float16* __restrict__ acts16, const int* __restrict__ pidx,
                           _Float16* __restrict__ sp) {
    int s = blockIdx.x, b = blockIdx.y;
    const _Float16* arow = acts16 + ((size_t)b * S_ + s) * NPROC;
    _Float16* orow = sp + ((size_t)b * S_ + s) * KPROC;
    const int* pi = pidx + (size_t)b * KPROC;
    for (int k = threadIdx.x; k < KPROC; k += 256) orow[k] = arow[pi[k]];
}

__global__ void k_gatherWoT(const _Float16* __restrict__ pout16, const int* __restrict__ pidx,
                            _Float16* __restrict__ woT) {
    __shared__ _Float16 t[64][65];
    int k0 = blockIdx.x * 64, d0 = blockIdx.y * 64, b = blockIdx.z;
    const int* pi = pidx + (size_t)b * KPROC;
    for (int i = threadIdx.x; i < 4096; i += 256) {
        int kk = i >> 6, dd = i & 63;
        t[kk][dd] = pout16[(size_t)pi[k0 + kk] * D_ + d0 + dd];
    }
    __syncthreads();
    for (int i = threadIdx.x; i < 4096; i += 256) {
        int dd = i >> 6, kk = i & 63;
        woT[((size_t)b * D_ + d0 + dd) * KPROC + k0 + kk] = t[kk][dd];
    }
}

// XOR-swizzle (round-2, measured 0 conflicts at 16x16; 32x32 reads are at worst 4-way):
// LDS physical chunk s of row r holds global chunk s ^ ((r>>1)&3).
// Writer permutes global source per lane; reader XORs its chunk index.

// ---------------- stage D body: sel_acts = gelu(x16 * (ph+pl)^T), 32x32x16 MFMA ----------------
__device__ __forceinline__ void dev_gemmD(
    const _Float16* __restrict__ x16, const _Float16* __restrict__ ph, const _Float16* __restrict__ pl,
    const int* __restrict__ iidx, _Float16* __restrict__ a16,
    _Float16* tA, _Float16* tBh, _Float16* tBl, int bx, int by, int b)
{
    const int m0 = bx * 128, n0 = by * 128;
    const int tid = threadIdx.x, lane = tid & 63;
    const int wave = tid >> 6, wrow = wave >> 1, wcol = wave & 1;
    const int srow = tid >> 2, spart = tid & 3;
    const int spe = spart ^ ((srow >> 1) & 3);

    const _Float16* as0 = x16 + ((size_t)b * S_ + m0 + srow) * D_ + spe * 8;
    const _Float16* as1 = as0 + (size_t)64 * D_;
    int r0 = iidx[(size_t)b * KIN + n0 + srow];
    int r1 = iidx[(size_t)b * KIN + n0 + srow + 64];
    const _Float16* bh0 = ph + (size_t)r0 * D_ + spe * 8;
    const _Float16* bh1 = ph + (size_t)r1 * D_ + spe * 8;
    const _Float16* bl0 = pl + (size_t)r0 * D_ + spe * 8;
    const _Float16* bl1 = pl + (size_t)r1 * D_ + spe * 8;

    v16f acc[2][2];
#pragma unroll
    for (int i = 0; i < 2; i++)
#pragma unroll
        for (int j = 0; j < 2; j++) acc[i][j] = (v16f)(0.0f);

    const int lrow = lane & 31, lhi = lane >> 5;
    const int swz = (lane >> 1) & 3;
    const int abase = (wrow * 64 + lrow) * 32;
    const int bbase = (wcol * 64 + lrow) * 32;

    for (int kt = 0; kt < D_; kt += 32) {
        __syncthreads();
        cp16(&tA[tid * 8], as0 + kt);
        cp16(&tA[2048 + tid * 8], as1 + kt);
        cp16(&tBh[tid * 8], bh0 + kt);
        cp16(&tBh[2048 + tid * 8], bh1 + kt);
        cp16(&tBl[tid * 8], bl0 + kt);
        cp16(&tBl[2048 + tid * 8], bl1 + kt);
        asm volatile("s_waitcnt vmcnt(0)" ::: "memory");
        __syncthreads();
        v8h af[2][2], fh[2][2], fl[2][2];
#pragma unroll
        for (int kw = 0; kw < 2; kw++) {
            const int ch = ((kw * 2 + lhi) ^ swz) * 8;
#pragma unroll
            for (int mi = 0; mi < 2; mi++) af[mi][kw] = *(const v8h*)&tA[abase + mi * 1024 + ch];
#pragma unroll
            for (int nj = 0; nj < 2; nj++) {
                fh[nj][kw] = *(const v8h*)&tBh[bbase + nj * 1024 + ch];
                fl[nj][kw] = *(const v8h*)&tBl[bbase + nj * 1024 + ch];
            }
        }
#pragma unroll
        for (int kw = 0; kw < 2; kw++)
#pragma unroll
            for (int mi = 0; mi < 2; mi++)
#pragma unroll
                for (int nj = 0; nj < 2; nj++) {
                    acc[mi][nj] = __builtin_amdgcn_mfma_f32_32x32x16_f16(af[mi][kw], fh[nj][kw], acc[mi][nj], 0, 0, 0);
                    acc[mi][nj] = __builtin_amdgcn_mfma_f32_32x32x16_f16(af[mi][kw], fl[nj][kw], acc[mi][nj], 0, 0, 0);
                }
    }
#pragma unroll
    for (int mi = 0; mi < 2; mi++)
#pragma unroll
        for (int nj = 0; nj < 2; nj++)
#pragma unroll
            for (int r = 0; r < 16; r++) {
                int row = (r & 3) + 8 * (r >> 2) + 4 * lhi;
                float gv = geluf(acc[mi][nj][r]);
                a16[((size_t)b * S_ + m0 + wrow * 64 + mi * 32 + row) * (size_t)KIN
                    + n0 + wcol * 64 + nj * 32 + lrow] = (_Float16)gv;
            }
}

__global__ __launch_bounds__(256, 3) void k_gemmD(
    const _Float16* __restrict__ x16, const _Float16* __restrict__ ph, const _Float16* __restrict__ pl,
    const int* __restrict__ iidx, _Float16* __restrict__ a16)
{
    __shared__ _Float16 tA[4096], tBh[4096], tBl[4096];
    dev_gemmD(x16, ph, pl, iidx, a16, tA, tBh, tBl, blockIdx.x, blockIdx.y, blockIdx.z);
}

// fused: z<4 -> gemmD batch z; z>=4 -> gatherW block (overlaps MFMA-bound D with HBM-bound gather)
__global__ __launch_bounds__(256, 3) void k_fusedDW(
    const _Float16* __restrict__ x16, const _Float16* __restrict__ ph, const _Float16* __restrict__ pl,
    const int* __restrict__ iidx, _Float16* __restrict__ a16,
    const float* __restrict__ pw, _Float16* __restrict__ Wh, _Float16* __restrict__ Wl, size_t wstride)
{
    __shared__ _Float16 tA[4096], tBh[4096], tBl[4096];
    if (blockIdx.z >= 4) {
        int idx = (blockIdx.z - 4) * 512 + blockIdx.y * 16 + blockIdx.x;  // [0, 16384)
        int p = idx >> 2, b = idx & 3;
        dev_gatherW(pw, iidx, Wh, Wl, p, b, (size_t)b * wstride);
        return;
    }
    dev_gemmD(x16, ph, pl, iidx, a16, tA, tBh, tBl, blockIdx.x, blockIdx.y, blockIdx.z);
}

__global__ void k_gatherW(const float* __restrict__ pw, const int* __restrict__ iidx,
                          _Float16* __restrict__ Wh, _Float16* __restrict__ Wl,
                          int b_base, size_t wstride) {
    dev_gatherW(pw, iidx, Wh, Wl, blockIdx.x, b_base + blockIdx.y, (size_t)blockIdx.y * wstride);
}

// ---------------- stage E: proc_acts = gelu(a16 * (Wh+Wl)^T), 32x32x16, scores += col sums ----------------
__global__ __launch_bounds__(256, 3) void k_gemmE(
    const _Float16* __restrict__ a16, const _Float16* __restrict__ Wh, const _Float16* __restrict__ Wl,
    _Float16* __restrict__ acts16, double* __restrict__ scores, int b_base, size_t wstride)
{
    const int b = b_base + blockIdx.z;
    const int m0 = blockIdx.x * 128, n0 = blockIdx.y * 128;
    __shared__ _Float16 tA[4096], tBh[4096], tBl[4096];
    const int tid = threadIdx.x, lane = tid & 63;
    const int wave = tid >> 6, wrow = wave >> 1, wcol = wave & 1;
    const int srow = tid >> 2, spart = tid & 3;
    const int spe = spart ^ ((srow >> 1) & 3);

    const _Float16* as0 = a16 + ((size_t)b * S_ + m0 + srow) * (size_t)KIN + spe * 8;
    const _Float16* as1 = as0 + (size_t)64 * KIN;
    const _Float16* whB = Wh + (size_t)blockIdx.z * wstride;
    const _Float16* wlB = Wl + (size_t)blockIdx.z * wstride;
    const _Float16* bh0 = whB + (size_t)(n0 + srow) * KIN + spe * 8;
    const _Float16* bh1 = bh0 + (size_t)64 * KIN;
    const _Float16* bl0 = wlB + (size_t)(n0 + srow) * KIN + spe * 8;
    const _Float16* bl1 = bl0 + (size_t)64 * KIN;

    v16f acc[2][2];
#pragma unroll
    for (int i = 0; i < 2; i++)
#pragma unroll
        for (int j = 0; j < 2; j++) acc[i][j] = (v16f)(0.0f);

    const int lrow = lane & 31, lhi = lane >> 5;
    const int swz = (lane >> 1) & 3;
    const int abase = (wrow * 64 + lrow) * 32;
    const int bbase = (wcol * 64 + lrow) * 32;

    for (int kt = 0; kt < KIN; kt += 32) {
        __syncthreads();
        cp16(&tA[tid * 8], as0 + kt);
        cp16(&tA[2048 + tid * 8], as1 + kt);
        cp16(&tBh[tid * 8], bh0 + kt);
        cp16(&tBh[2048 + tid * 8], bh1 + kt);
        cp16(&tBl[tid * 8], bl0 + kt);
        cp16(&tBl[2048 + tid * 8], bl1 + kt);
        asm volatile("s_waitcnt vmcnt(0)" ::: "memory");
        __syncthreads();
        v8h af[2][2], fh[2][2], fl[2][2];
#pragma unroll
        for (int kw = 0; kw < 2; kw++) {
            const int ch = ((kw * 2 + lhi) ^ swz) * 8;
#pragma unroll
            for (int mi = 0; mi < 2; mi++) af[mi][kw] = *(const v8h*)&tA[abase + mi * 1024 + ch];
#pragma unroll
            for (int nj = 0; nj < 2; nj++) {
                fh[nj][kw] = *(const v8h*)&tBh[bbase + nj * 1024 + ch];
                fl[nj][kw] = *(const v8h*)&tBl[bbase + nj * 1024 + ch];
            }
        }
#pragma unroll
        for (int kw = 0; kw < 2; kw++)
#pragma unroll
            for (int mi = 0; mi < 2; mi++)
#pragma unroll
                for (int nj = 0; nj < 2; nj++) {
                    acc[mi][nj] = __builtin_amdgcn_mfma_f32_32x32x16_f16(af[mi][kw], fh[nj][kw], acc[mi][nj], 0, 0, 0);
                    acc[mi][nj] = __builtin_amdgcn_mfma_f32_32x32x16_f16(af[mi][kw], fl[nj][kw], acc[mi][nj], 0, 0, 0);
                }
    }
    float psum[2] = {0.f, 0.f};
#pragma unroll
    for (int mi = 0; mi < 2; mi++)
#pragma unroll
        for (int nj = 0; nj < 2; nj++)
#pragma unroll
            for (int r = 0; r < 16; r++) {
                int row = (r & 3) + 8 * (r >> 2) + 4 * lhi;
                float gv = geluf(acc[mi][nj][r]);
                acts16[((size_t)b * S_ + m0 + wrow * 64 + mi * 32 + row) * (size_t)NPROC
                       + n0 + wcol * 64 + nj * 32 + lrow] = (_Float16)gv;
                psum[nj] += gv;
            }
#pragma unroll
    for (int nj = 0; nj < 2; nj++) {
        float s = psum[nj];
        s += __shfl_xor(s, 32, 64);
        if (lhi == 0)
            atomicAdd(&scores[(size_t)b * NPROC + n0 + wcol * 64 + nj * 32 + lrow], (double)s);
    }
}

// ---------------- stage F: out = sp * woT^T (plain f16, 32x32x16) ----------------
__global__ __launch_bounds__(256, 3) void k_gemmF(
    const _Float16* __restrict__ sp, const _Float16* __restrict__ woT, float* __restrict__ out)
{
    const int b = blockIdx.z;
    const int m0 = blockIdx.x * 128, n0 = blockIdx.y * 128;
    __shared__ _Float16 tA[4096], tB[4096];
    const int tid = threadIdx.x, lane = tid & 63;
    const int wave = tid >> 6, wrow = wave >> 1, wcol = wave & 1;
    const int srow = tid >> 2, spart = tid & 3;
    const int spe = spart ^ ((srow >> 1) & 3);

    const _Float16* as0 = sp + ((size_t)b * S_ + m0 + srow) * (size_t)KPROC + spe * 8;
    const _Float16* as1 = as0 + (size_t)64 * KPROC;
    const _Float16* bs0 = woT + ((size_t)b * D_ + n0 + srow) * (size_t)KPROC + spe * 8;
    const _Float16* bs1 = bs0 + (size_t)64 * KPROC;

    v16f acc[2][2];
#pragma unroll
    for (int i = 0; i < 2; i++)
#pragma unroll
        for (int j = 0; j < 2; j++) acc[i][j] = (v16f)(0.0f);

    const int lrow = lane & 31, lhi = lane >> 5;
    const int swz = (lane >> 1) & 3;
    const int abase = (wrow * 64 + lrow) * 32;
    const int bbase = (wcol * 64 + lrow) * 32;

    for (int kt = 0; kt < KPROC; kt += 32) {
        __syncthreads();
        cp16(&tA[tid * 8], as0 + kt);
        cp16(&tA[2048 + tid * 8], as1 + kt);
        cp16(&tB[tid * 8], bs0 + kt);
        cp16(&tB[2048 + tid * 8], bs1 + kt);
        asm volatile("s_waitcnt vmcnt(0)" ::: "memory");
        __syncthreads();
        v8h af[2][2], bf[2][2];
#pragma unroll
        for (int kw = 0; kw < 2; kw++) {
            const int ch = ((kw * 2 + lhi) ^ swz) * 8;
#pragma unroll
            for (int mi = 0; mi < 2; mi++) af[mi][kw] = *(const v8h*)&tA[abase + mi * 1024 + ch];
#pragma unroll
            for (int nj = 0; nj < 2; nj++) bf[nj][kw] = *(const v8h*)&tB[bbase + nj * 1024 + ch];
        }
#pragma unroll
        for (int kw = 0; kw < 2; kw++)
#pragma unroll
            for (int mi = 0; mi < 2; mi++)
#pragma unroll
                for (int nj = 0; nj < 2; nj++)
                    acc[mi][nj] = __builtin_amdgcn_mfma_f32_32x32x16_f16(af[mi][kw], bf[nj][kw], acc[mi][nj], 0, 0, 0);
    }
#pragma unroll
    for (int mi = 0; mi < 2; mi++)
#pragma unroll
        for (int nj = 0; nj < 2; nj++)
#pragma unroll
            for (int r = 0; r < 16; r++) {
                int row = (r & 3) + 8 * (r >> 2) + 4 * lhi;
                out[((size_t)b * S_ + m0 + wrow * 64 + mi * 32 + row) * (size_t)D_
                    + n0 + wcol * 64 + nj * 32 + lrow] = acc[mi][nj][r];
            }
}

// ---------------- host ----------------
extern "C" void kernel_launch(void* const* d_in, const int* in_sizes, int n_in,
                              void* d_out, int out_size, void* d_ws, size_t ws_size,
                              hipStream_t stream) {
    const float* x    = (const float*)d_in[0];
    const float* W1   = (const float*)d_in[1];
    const float* b1   = (const float*)d_in[2];
    const float* lng  = (const float*)d_in[3];
    const float* lnb  = (const float*)d_in[4];
    const float* W2   = (const float*)d_in[5];
    const float* b2   = (const float*)d_in[6];
    const float* keys = (const float*)d_in[7];
    const float* patt = (const float*)d_in[8];
    const float* pw   = (const float*)d_in[9];
    const float* pout = (const float*)d_in[10];
    (void)in_sizes; (void)n_in; (void)out_size;

    char* w = (char*)d_ws;
    size_t off = 0;
    auto alloc = [&](size_t bytes) -> void* {
        void* p = w + off;
        off += (bytes + 255) & ~(size_t)255;
        return p;
    };
    double* gc64   = (double*)alloc((size_t)B_ * D_ * 8);
    float*  pmax   = (float*) alloc((size_t)B_ * 16 * D_ * 4);
    double* logits = (double*)alloc((size_t)B_ * NIN * 8);
    double* scores = (double*)alloc((size_t)B_ * NPROC * 8);
    double* hpre   = (double*)alloc((size_t)B_ * DR2 * 8);
    double* qs     = (double*)alloc((size_t)B_ * DR * 8);
    int*    iidx   = (int*)   alloc((size_t)B_ * KIN * 4);
    int*    pidx   = (int*)   alloc((size_t)B_ * KPROC * 4);
    _Float16* a16    = (_Float16*)alloc((size_t)B_ * S_ * KIN * 2);    // 67 MB
    _Float16* acts16 = (_Float16*)alloc((size_t)B_ * S_ * NPROC * 2);  // 67 MB
    _Float16* pout16 = (_Float16*)alloc((size_t)NPROC * D_ * 2);       // 8.4 MB
    char* u1 = (char*)alloc((size_t)67108864);
    _Float16* x16 = (_Float16*)u1;
    _Float16* ph  = (_Float16*)(u1 + 16777216);
    _Float16* pl  = (_Float16*)(u1 + 33554432);
    _Float16* WhT = (_Float16*)u1;               // thin path, one batch
    _Float16* WlT = (_Float16*)(u1 + 33554432);
    _Float16* sp  = (_Float16*)u1;
    _Float16* woT = (_Float16*)(u1 + 33554432);

    const size_t WSTRIDE = (size_t)NPROC * KIN;
    size_t off_before_fat = off;
    _Float16* WhA = (_Float16*)alloc((size_t)B_ * WSTRIDE * 2);
    _Float16* WlA = (_Float16*)alloc((size_t)B_ * WSTRIDE * 2);
    bool fat = (off <= ws_size);
    if (!fat) off = off_before_fat;

    hipMemsetAsync(scores, 0, (size_t)B_ * NPROC * 8, stream);

    k_conv_x16 <<<dim3((B_ * S_ * D_ / 4 + 255) / 256), 256, 0, stream>>>(x, x16, B_ * S_ * D_ / 4);
    k_conv_split<<<dim3((NIN * D_ + 255) / 256), 256, 0, stream>>>(patt, ph, pl, NIN * D_);
    k_conv_x16 <<<dim3((NPROC * D_ / 4 + 255) / 256), 256, 0, stream>>>(pout, pout16, NPROC * D_ / 4);

    k_max1<<<dim3(4, 16, 4), 256, 0, stream>>>(x, pmax);
    k_max2<<<dim3(4, 4), 256, 0, stream>>>(pmax, gc64);
    k_router1<<<dim3(128, 4), 256, 0, stream>>>(gc64, W1, b1, hpre);
    k_router2<<<dim3(4), 512, 0, stream>>>(hpre, lng, lnb, W2, b2, qs);
    k_router3<<<dim3(2048, 4), 256, 0, stream>>>(qs, keys, logits);
    k_topk<NIN, KIN><<<dim3(4), 1024, 0, stream>>>(logits, iidx);

    if (fat) {
        // one launch: D (z<4, MFMA-bound, dispatched first) + all-batch gatherW (z>=4, HBM-bound) overlap
        k_fusedDW<<<dim3(16, 32, 36), 256, 0, stream>>>(x16, ph, pl, iidx, a16, pw, WhA, WlA, WSTRIDE);
        k_gemmE<<<dim3(16, 32, 4), 256, 0, stream>>>(a16, WhA, WlA, acts16, scores, 0, WSTRIDE);
    } else {
        k_gemmD<<<dim3(16, 32, 4), 256, 0, stream>>>(x16, ph, pl, iidx, a16);
        for (int b = 0; b < 4; b++) {
            k_gatherW<<<dim3(NPROC, 1), 256, 0, stream>>>(pw, iidx, WhT, WlT, b, 0);
            k_gemmE<<<dim3(16, 32, 1), 256, 0, stream>>>(a16, WhT, WlT, acts16, scores, b, 0);
        }
    }

    k_topk<NPROC, KPROC><<<dim3(4), 1024, 0, stream>>>(scores, pidx);
    k_gatherSP<<<dim3(S_, 4), 256, 0, stream>>>(acts16, pidx, sp);
    k_gatherWoT<<<dim3(KPROC / 64, D_ / 64, 4), 256, 0, stream>>>(pout16, pidx, woT);
    k_gemmF<<<dim3(16, 8, 4), 256, 0, stream>>>(sp, woT, (float*)d_out);
}